// Round 1
// baseline (737.078 us; speedup 1.0000x reference)
//
#include <hip/hip_runtime.h>
#include <hip/hip_bf16.h>
#include <cstdint>
#include <cstddef>

// Problem constants
#define Bq 4
#define Mq 4
#define Lseq 512
#define Dmod 1024
#define Hq 16
#define DHq 64

using bf16 = __bf16;
using bf16x4 = __attribute__((ext_vector_type(4))) __bf16;
using bf16x8 = __attribute__((ext_vector_type(8))) __bf16;
using f32x4 = __attribute__((ext_vector_type(4))) float;

// -------- async global->LDS, 16B per lane (m97 pattern) --------
__device__ __forceinline__ void gld_lds16(const bf16* g, bf16* l) {
  __builtin_amdgcn_global_load_lds(
      (const __attribute__((address_space(1))) void*)g,
      (__attribute__((address_space(3))) void*)l, 16, 0, 0);
}

// =====================================================================
// GEMM core: C[BM,BN] = A[BM,K] * Bt[BN,K]^T, bf16 in, f32 accum.
// BK=32, 256 threads. LDS layout [row][32] contiguous (required by
// global_load_lds lane ordering: dest = wave-uniform base + lane*16B).
// =====================================================================
template <int WAVES_M, int WAVES_N, int WTM, int WTN>
__device__ __forceinline__ void gemm_core(const bf16* __restrict__ A,
                                          const bf16* __restrict__ Bt,
                                          int K, int lda, int ldb,
                                          bf16* As, bf16* Bs,
                                          f32x4 (&acc)[WTM][WTN]) {
  constexpr int BM = WAVES_M * WTM * 16;
  constexpr int BN = WAVES_N * WTN * 16;
  constexpr int IA = BM / 64;
  constexpr int IB = BN / 64;

  const int t = threadIdx.x;
  const int lane = t & 63;
  const int wave = t >> 6;
  const int wm = wave % WAVES_M;
  const int wn = wave / WAVES_M;
  const int r = t >> 2;            // staging row (0..63)
  const int c8 = (t & 3) * 8;      // staging col (bf16 elems)
  const int fr = lane & 15;        // fragment row/col within 16-tile
  const int fk = (lane >> 4) * 8;  // fragment k offset

  const bf16* Ab = A + (size_t)r * lda + c8;
  const bf16* Bb = Bt + (size_t)r * ldb + c8;

  for (int k0 = 0; k0 < K; k0 += 32) {
    if (k0) __syncthreads();  // protect LDS from previous iter's readers
#pragma unroll
    for (int i = 0; i < IA; ++i)
      gld_lds16(Ab + (size_t)i * 64 * lda + k0, As + i * 2048 + t * 8);
#pragma unroll
    for (int i = 0; i < IB; ++i)
      gld_lds16(Bb + (size_t)i * 64 * ldb + k0, Bs + i * 2048 + t * 8);
    asm volatile("s_waitcnt vmcnt(0)" ::: "memory");
    __syncthreads();

    bf16x8 af[WTM], bfv[WTN];
#pragma unroll
    for (int i = 0; i < WTM; ++i)
      af[i] = *(const bf16x8*)(As + (wm * WTM * 16 + i * 16 + fr) * 32 + fk);
#pragma unroll
    for (int j = 0; j < WTN; ++j)
      bfv[j] = *(const bf16x8*)(Bs + (wn * WTN * 16 + j * 16 + fr) * 32 + fk);
#pragma unroll
    for (int i = 0; i < WTM; ++i)
#pragma unroll
      for (int j = 0; j < WTN; ++j)
        acc[i][j] = __builtin_amdgcn_mfma_f32_16x16x32_bf16(af[i], bfv[j],
                                                            acc[i][j], 0, 0, 0);
  }
}

// -------- plain 128x128 GEMM: C = A * Bt^T (bf16 store) --------
__global__ __launch_bounds__(256) void gemm_bt_128(
    const bf16* __restrict__ A, const bf16* __restrict__ Bt,
    bf16* __restrict__ C, int K, int lda, int ldb, int ldc) {
  __shared__ __align__(16) bf16 As[128 * 32];
  __shared__ __align__(16) bf16 Bs[128 * 32];
  f32x4 acc[4][4] = {};
  const bf16* Ab = A + (size_t)blockIdx.y * 128 * lda;
  const bf16* Bb = Bt + (size_t)blockIdx.x * 128 * ldb;
  gemm_core<2, 2, 4, 4>(Ab, Bb, K, lda, ldb, As, Bs, acc);

  const int t = threadIdx.x, lane = t & 63, wave = t >> 6;
  const int wm = wave & 1, wn = wave >> 1;
  const int cr = (lane >> 4) * 4, cc = lane & 15;
  const size_t row0 = (size_t)blockIdx.y * 128 + wm * 64;
  const size_t col0 = (size_t)blockIdx.x * 128 + wn * 64;
#pragma unroll
  for (int i = 0; i < 4; ++i)
#pragma unroll
    for (int j = 0; j < 4; ++j)
#pragma unroll
      for (int rg = 0; rg < 4; ++rg)
        C[(row0 + i * 16 + cr + rg) * ldc + col0 + j * 16 + cc] =
            (bf16)acc[i][j][rg];
}

// -------- final GEMM: C(f32) = A*Bt^T + resid(f32) --------
__global__ __launch_bounds__(256) void gemm_bt_resid(
    const bf16* __restrict__ A, const bf16* __restrict__ Bt,
    const float* __restrict__ resid, float* __restrict__ C, int K, int lda,
    int ldb, int ldc) {
  __shared__ __align__(16) bf16 As[128 * 32];
  __shared__ __align__(16) bf16 Bs[128 * 32];
  f32x4 acc[4][4] = {};
  const bf16* Ab = A + (size_t)blockIdx.y * 128 * lda;
  const bf16* Bb = Bt + (size_t)blockIdx.x * 128 * ldb;
  gemm_core<2, 2, 4, 4>(Ab, Bb, K, lda, ldb, As, Bs, acc);

  const int t = threadIdx.x, lane = t & 63, wave = t >> 6;
  const int wm = wave & 1, wn = wave >> 1;
  const int cr = (lane >> 4) * 4, cc = lane & 15;
  const size_t row0 = (size_t)blockIdx.y * 128 + wm * 64;
  const size_t col0 = (size_t)blockIdx.x * 128 + wn * 64;
#pragma unroll
  for (int i = 0; i < 4; ++i)
#pragma unroll
    for (int j = 0; j < 4; ++j)
#pragma unroll
      for (int rg = 0; rg < 4; ++rg) {
        size_t idx = (row0 + i * 16 + cr + rg) * ldc + col0 + j * 16 + cc;
        C[idx] = acc[i][j][rg] + resid[idx];
      }
}

// -------- scores GEMM: S = qh * qih^T per (b,m,h); epilogue does
// mask + exp(s-1) (fixed shift valid: |cos sim| <= ~1); unnormalized p
// written f32 into the attn output region. NEW: per-row partial sums are
// shfl-reduced across the 16-lane column group and atomicAdd'ed into
// denom[B,H,L] (joint softmax over (m,lk) => denominator indexed (b,h,lq)).
__global__ __launch_bounds__(256) void gemm_scores(
    const bf16* __restrict__ qh, const bf16* __restrict__ qih,
    const int* __restrict__ mask, float* __restrict__ attn,
    float* __restrict__ denom) {
  __shared__ __align__(16) bf16 As[128 * 32];
  __shared__ __align__(16) bf16 Bs[128 * 32];
  f32x4 acc[4][4] = {};
  const int z = blockIdx.z;  // (b*M+m)*H + h
  const int bm = z >> 4, h = z & 15;
  const bf16* Ab = qh + (size_t)bm * Lseq * Dmod + h * DHq +
                   (size_t)blockIdx.y * 128 * Dmod;
  const bf16* Bb = qih + (size_t)bm * Lseq * Dmod + h * DHq +
                   (size_t)blockIdx.x * 128 * Dmod;
  gemm_core<2, 2, 4, 4>(Ab, Bb, DHq, Dmod, Dmod, As, Bs, acc);

  const int* mrow = mask + (size_t)bm * Lseq * Lseq;
  float* crow = attn + (size_t)z * Lseq * Lseq;
  float* drow = denom + ((size_t)(bm >> 2) * Hq + h) * Lseq;  // b = bm>>2
  const int t = threadIdx.x, lane = t & 63, wave = t >> 6;
  const int wm = wave & 1, wn = wave >> 1;
  const int cr = (lane >> 4) * 4, cc = lane & 15;
  const int row0 = blockIdx.y * 128 + wm * 64;
  const int col0 = blockIdx.x * 128 + wn * 64;
#pragma unroll
  for (int i = 0; i < 4; ++i)
#pragma unroll
    for (int rg = 0; rg < 4; ++rg) {
      const size_t grow = row0 + i * 16 + cr + rg;
      float rs = 0.0f;
#pragma unroll
      for (int j = 0; j < 4; ++j) {
        const size_t gcol = col0 + j * 16 + cc;
        float o = 0.0f;
        if (mrow[grow * Lseq + gcol] != 0)
          o = __expf(acc[i][j][rg] - 1.0f);
        crow[grow * Lseq + gcol] = o;
        rs += o;
      }
      // reduce across the 16 lanes sharing this row (cc = lane&15)
      rs += __shfl_xor(rs, 1);
      rs += __shfl_xor(rs, 2);
      rs += __shfl_xor(rs, 4);
      rs += __shfl_xor(rs, 8);
      if ((lane & 15) == 0) atomicAdd(drow + grow, rs);
    }
}

// -------- PV GEMM: out_h = attn(f32, unnormalized) * qih (via qih_t as Bt).
// A staged via registers; each streamed attn value is scaled by the
// per-row 1/denom (hoisted out of the K loop) and the NORMALIZED value is
// written back to the attn output in the same pass (race-free: each
// (z, blockIdx.y) block exclusively owns its 128 rows; each element is
// touched by exactly one thread once). This replaces the attn_norm pass.
__global__ __launch_bounds__(256) void gemm_pv(float* __restrict__ attn,
                                               const bf16* __restrict__ qih_t,
                                               const float* __restrict__ denom,
                                               bf16* __restrict__ outh) {
  __shared__ __align__(16) bf16 As[128 * 32];
  __shared__ __align__(16) bf16 Bs[64 * 32];
  f32x4 acc[2][4] = {};
  const int z = blockIdx.z;
  const int bm = z >> 4, h = z & 15;
  float* Ab = attn + (size_t)z * Lseq * Lseq + (size_t)blockIdx.y * 128 * Lseq;
  const bf16* Bb = qih_t + (size_t)z * DHq * Lseq;

  const int t = threadIdx.x;
  const int lane = t & 63;
  const int wave = t >> 6;
  const int ra = t >> 3;           // A staging row base (0..31)
  const int ca = (t & 7) * 4;      // A staging col (f32 elems)
  const int rb = t >> 2;           // B staging row (0..63)
  const int cb = (t & 3) * 8;      // B staging col
  const int fr = lane & 15;
  const int fk = (lane >> 4) * 8;

  // 1/denom for the 4 rows this thread stages (constant across K)
  float inv_d[4];
  const float* dz =
      denom + ((size_t)(bm >> 2) * Hq + h) * Lseq + blockIdx.y * 128;
#pragma unroll
  for (int i = 0; i < 4; ++i) {
    const float d = dz[i * 32 + ra];
    inv_d[i] = (d > 0.0f) ? 1.0f / d : 0.0f;
  }

  for (int k0 = 0; k0 < Lseq; k0 += 32) {
    float4 va[4];
#pragma unroll
    for (int i = 0; i < 4; ++i) {
      float* ap = Ab + (size_t)(i * 32 + ra) * Lseq + k0 + ca;
      va[i] = *(const float4*)ap;
      va[i].x *= inv_d[i]; va[i].y *= inv_d[i];
      va[i].z *= inv_d[i]; va[i].w *= inv_d[i];
      *(float4*)ap = va[i];  // write normalized attn back (output)
    }
    if (k0) __syncthreads();
#pragma unroll
    for (int i = 0; i < 4; ++i) {
      bf16x4 o;
      o[0] = (bf16)va[i].x; o[1] = (bf16)va[i].y;
      o[2] = (bf16)va[i].z; o[3] = (bf16)va[i].w;
      *(bf16x4*)(As + (i * 32 + ra) * 32 + ca) = o;
    }
    gld_lds16(Bb + (size_t)rb * Lseq + k0 + cb, Bs + t * 8);
    asm volatile("s_waitcnt vmcnt(0)" ::: "memory");
    __syncthreads();

    bf16x8 af[2], bfv[4];
#pragma unroll
    for (int i = 0; i < 2; ++i)
      af[i] = *(const bf16x8*)(As + (wave * 32 + i * 16 + fr) * 32 + fk);
#pragma unroll
    for (int j = 0; j < 4; ++j)
      bfv[j] = *(const bf16x8*)(Bs + (j * 16 + fr) * 32 + fk);
#pragma unroll
    for (int i = 0; i < 2; ++i)
#pragma unroll
      for (int j = 0; j < 4; ++j)
        acc[i][j] = __builtin_amdgcn_mfma_f32_16x16x32_bf16(af[i], bfv[j],
                                                            acc[i][j], 0, 0, 0);
  }

  bf16* Cb = outh + (size_t)bm * Lseq * Dmod + h * DHq;
  const int cr = (lane >> 4) * 4, cc = lane & 15;
  const size_t row0 = (size_t)blockIdx.y * 128 + wave * 32;
#pragma unroll
  for (int i = 0; i < 2; ++i)
#pragma unroll
    for (int j = 0; j < 4; ++j)
#pragma unroll
      for (int rg = 0; rg < 4; ++rg)
        Cb[(row0 + i * 16 + cr + rg) * Dmod + j * 16 + cc] =
            (bf16)acc[i][j][rg];
}

// -------- LayerNorm over D=1024, f32 in -> bf16 out, one block/row -------
__global__ __launch_bounds__(256) void ln_kernel(const float* __restrict__ q,
                                                 const float* __restrict__ g,
                                                 const float* __restrict__ b,
                                                 bf16* __restrict__ qn) {
  const size_t row = blockIdx.x;
  const float* x = q + row * Dmod;
  bf16* y = qn + row * Dmod;
  const int t = threadIdx.x;
  float4 v = *(const float4*)(x + t * 4);
  float s = v.x + v.y + v.z + v.w;
  float ss = v.x * v.x + v.y * v.y + v.z * v.z + v.w * v.w;
  for (int off = 32; off; off >>= 1) {
    s += __shfl_xor(s, off);
    ss += __shfl_xor(ss, off);
  }
  __shared__ float sm[8];
  const int wave = t >> 6, lane = t & 63;
  if (lane == 0) { sm[wave * 2] = s; sm[wave * 2 + 1] = ss; }
  __syncthreads();
  s = sm[0] + sm[2] + sm[4] + sm[6];
  ss = sm[1] + sm[3] + sm[5] + sm[7];
  const float mean = s * (1.0f / Dmod);
  const float var = ss * (1.0f / Dmod) - mean * mean;
  const float rstd = rsqrtf(var + 1e-6f);
  float4 gg = *(const float4*)(g + t * 4);
  float4 bb = *(const float4*)(b + t * 4);
  bf16x4 o;
  o[0] = (bf16)((v.x - mean) * rstd * gg.x + bb.x);
  o[1] = (bf16)((v.y - mean) * rstd * gg.y + bb.y);
  o[2] = (bf16)((v.z - mean) * rstd * gg.z + bb.z);
  o[3] = (bf16)((v.w - mean) * rstd * gg.w + bb.w);
  *(bf16x4*)(y + t * 4) = o;
}

// -------- f32 -> bf16 bulk convert (for qi) --------
__global__ __launch_bounds__(256) void cvt_f32_bf16(const float* __restrict__ in,
                                                    bf16* __restrict__ out) {
  const size_t i = ((size_t)blockIdx.x * 256 + threadIdx.x) * 4;
  float4 v = *(const float4*)(in + i);
  bf16x4 o;
  o[0] = (bf16)v.x; o[1] = (bf16)v.y; o[2] = (bf16)v.z; o[3] = (bf16)v.w;
  *(bf16x4*)(out + i) = o;
}

// -------- L2 normalize each contiguous 64-elem chunk (one wave each) ----
__global__ __launch_bounds__(256) void l2norm_kernel(bf16* __restrict__ x) {
  const size_t chunk = (size_t)blockIdx.x * 4 + (threadIdx.x >> 6);
  const int lane = threadIdx.x & 63;
  bf16* p = x + chunk * 64;
  const float v = (float)p[lane];
  float s = v * v;
  for (int off = 32; off; off >>= 1) s += __shfl_xor(s, off);
  const float r = (s > 0.0f) ? rsqrtf(s) : 0.0f;
  p[lane] = (bf16)(v * r);
}

// -------- 64x64 tiled transpose, f32 in -> bf16 out ------
__global__ __launch_bounds__(256) void transpose64_f32(
    const float* __restrict__ in, bf16* __restrict__ out, int ld_in,
    int ld_out) {
  __shared__ bf16 tile[64 * 65];
  const int r0 = blockIdx.y * 64, c0 = blockIdx.x * 64;
  const int t = threadIdx.x, cl = t & 63, rq = t >> 6;
#pragma unroll
  for (int it = 0; it < 16; ++it) {
    const int rl = it * 4 + rq;
    tile[cl * 65 + rl] = (bf16)in[(size_t)(r0 + rl) * ld_in + c0 + cl];
  }
  __syncthreads();
#pragma unroll
  for (int it = 0; it < 16; ++it) {
    const int ol = it * 4 + rq;
    out[(size_t)(c0 + ol) * ld_out + r0 + cl] = tile[ol * 65 + cl];
  }
}

// -------- per-(b,m,h) transpose of qih [512,64]->[64,512] for PV Bt ------
__global__ __launch_bounds__(256) void transpose_qih(
    const bf16* __restrict__ qih, bf16* __restrict__ qih_t) {
  __shared__ bf16 tile[64 * 65];
  const int z = blockIdx.z;
  const int bm = z >> 4, h = z & 15;
  const bf16* in = qih + (size_t)bm * Lseq * Dmod + h * DHq;  // 512x64 ld 1024
  bf16* out = qih_t + (size_t)z * DHq * Lseq;                 // 64x512 ld 512
  const int r0 = blockIdx.x * 64;  // lk tile
  const int t = threadIdx.x, cl = t & 63, rq = t >> 6;
#pragma unroll
  for (int it = 0; it < 16; ++it) {
    const int rl = it * 4 + rq;
    tile[cl * 65 + rl] = in[(size_t)(r0 + rl) * Dmod + cl];
  }
  __syncthreads();
#pragma unroll
  for (int it = 0; it < 16; ++it) {
    const int dh = it * 4 + rq;
    out[(size_t)dh * Lseq + r0 + cl] = tile[dh * 65 + cl];
  }
}

extern "C" void kernel_launch(void* const* d_in, const int* in_sizes, int n_in,
                              void* d_out, int out_size, void* d_ws,
                              size_t ws_size, hipStream_t stream) {
  // Inputs f32 (reference dtype); outputs f32 (reference output dtype).
  const float* q = (const float*)d_in[0];
  // d_in[1] = k, unused by the reference forward
  const float* qi = (const float*)d_in[2];
  const int* mask = (const int*)d_in[3];
  const float* w_qs = (const float*)d_in[4];
  const float* w_qis = (const float*)d_in[5];
  const float* w_fc = (const float*)d_in[6];
  const float* ln_g = (const float*)d_in[7];
  const float* ln_b = (const float*)d_in[8];

  float* out = (float*)d_out;
  const size_t NE = (size_t)Bq * Mq * Lseq * Dmod;  // 8,388,608
  float* attn = out + NE;  // second tuple element (67,108,864 f32)

  // Scratch parked in the attn output region (dead before gemm_scores):
  char* attnc = (char*)attn;  // 268 MB available
  bf16* qib = (bf16*)attnc;                       // 16 MB
  bf16* wqs_t = (bf16*)(attnc + (16u << 20));     // 2 MB
  bf16* wqis_t = (bf16*)(attnc + (18u << 20));    // 2 MB

  char* ws = (char*)d_ws;
  const size_t SZ = NE * sizeof(bf16);  // 16 MiB
  bf16* qn = (bf16*)(ws);               // LN out; reused as out_h later
  bf16* qh = (bf16*)(ws + SZ);
  bf16* qih = (bf16*)(ws + 2 * SZ);
  bf16* qih_t = (bf16*)(ws + 3 * SZ);
  bf16* wfc_t = (bf16*)(ws + 4 * SZ);   // must survive to the last GEMM
  float* denom = (float*)(ws + 4 * SZ + (2u << 20));  // [B,H,L] = 128 KB
  bf16* outh = qn;                      // qn dead after first projection

  const int ROWS = Bq * Mq * Lseq;  // 8192

  // 1) input conversions / weight transposes (Bt layout for gemm core)
  cvt_f32_bf16<<<NE / 1024, 256, 0, stream>>>(qi, qib);
  transpose64_f32<<<dim3(16, 16), 256, 0, stream>>>(w_qs, wqs_t, Dmod, Dmod);
  transpose64_f32<<<dim3(16, 16), 256, 0, stream>>>(w_qis, wqis_t, Dmod, Dmod);
  transpose64_f32<<<dim3(16, 16), 256, 0, stream>>>(w_fc, wfc_t, Dmod, Dmod);
  hipMemsetAsync(denom, 0, (size_t)Bq * Hq * Lseq * sizeof(float), stream);

  // 2) LayerNorm(q) -> qn
  ln_kernel<<<ROWS, 256, 0, stream>>>(q, ln_g, ln_b, qn);

  // 3) projections
  gemm_bt_128<<<dim3(Dmod / 128, ROWS / 128), 256, 0, stream>>>(
      qn, wqs_t, qh, Dmod, Dmod, Dmod, Dmod);
  gemm_bt_128<<<dim3(Dmod / 128, ROWS / 128), 256, 0, stream>>>(
      qib, wqis_t, qih, Dmod, Dmod, Dmod, Dmod);

  // 4) per-head L2 normalize (in place; head chunks are contiguous 64)
  l2norm_kernel<<<ROWS * Hq / 4, 256, 0, stream>>>(qh);
  l2norm_kernel<<<ROWS * Hq / 4, 256, 0, stream>>>(qih);

  // 5) qih^T per (b,m,h) for the PV gemm's Bt operand
  transpose_qih<<<dim3(Lseq / 64, 1, Bq * Mq * Hq), 256, 0, stream>>>(qih,
                                                                      qih_t);

  // 6) scores + mask + exp(s-1) -> unnormalized p (f32) in attn region,
  //    with fused denominator accumulation into denom[B,H,L]
  gemm_scores<<<dim3(Lseq / 128, Lseq / 128, Bq * Mq * Hq), 256, 0, stream>>>(
      qh, qih, mask, attn, denom);

  // 7) out_h = attn @ qih; A rows scaled by 1/denom during staging and the
  //    normalized attn written back in the same pass (replaces attn_norm)
  gemm_pv<<<dim3(1, Lseq / 128, Bq * Mq * Hq), 256, 0, stream>>>(
      attn, qih_t, denom, outh);

  // 8) out = out_h @ w_fc + q (f32 out, f32 residual)
  gemm_bt_resid<<<dim3(Dmod / 128, ROWS / 128), 256, 0, stream>>>(
      outh, wfc_t, q, out, Dmod, Dmod, Dmod, Dmod);
}

// Round 4
// 615.628 us; speedup vs baseline: 1.1973x; 1.1973x over previous
//
#include <hip/hip_runtime.h>
#include <hip/hip_bf16.h>
#include <cstdint>
#include <cstddef>

// Problem constants
#define Bq 4
#define Mq 4
#define Lseq 512
#define Dmod 1024
#define Hq 16
#define DHq 64

using bf16 = __bf16;
using bf16x4 = __attribute__((ext_vector_type(4))) __bf16;
using bf16x8 = __attribute__((ext_vector_type(8))) __bf16;
using f32x4 = __attribute__((ext_vector_type(4))) float;

// -------- async global->LDS, 16B per lane (m97 pattern) --------
__device__ __forceinline__ void gld_lds16(const bf16* g, bf16* l) {
  __builtin_amdgcn_global_load_lds(
      (const __attribute__((address_space(1))) void*)g,
      (__attribute__((address_space(3))) void*)l, 16, 0, 0);
}

// =====================================================================
// GEMM core: C[BM,BN] = A[BM,K] * Bt[BN,K]^T, bf16 in, f32 accum.
// BK=32, 256 threads. LDS layout [row][32] contiguous (required by
// global_load_lds lane ordering: dest = wave-uniform base + lane*16B).
// =====================================================================
template <int WAVES_M, int WAVES_N, int WTM, int WTN>
__device__ __forceinline__ void gemm_core(const bf16* __restrict__ A,
                                          const bf16* __restrict__ Bt,
                                          int K, int lda, int ldb,
                                          bf16* As, bf16* Bs,
                                          f32x4 (&acc)[WTM][WTN]) {
  constexpr int BM = WAVES_M * WTM * 16;
  constexpr int BN = WAVES_N * WTN * 16;
  constexpr int IA = BM / 64;
  constexpr int IB = BN / 64;

  const int t = threadIdx.x;
  const int lane = t & 63;
  const int wave = t >> 6;
  const int wm = wave % WAVES_M;
  const int wn = wave / WAVES_M;
  const int r = t >> 2;            // staging row (0..63)
  const int c8 = (t & 3) * 8;      // staging col (bf16 elems)
  const int fr = lane & 15;        // fragment row/col within 16-tile
  const int fk = (lane >> 4) * 8;  // fragment k offset

  const bf16* Ab = A + (size_t)r * lda + c8;
  const bf16* Bb = Bt + (size_t)r * ldb + c8;

  for (int k0 = 0; k0 < K; k0 += 32) {
    if (k0) __syncthreads();  // protect LDS from previous iter's readers
#pragma unroll
    for (int i = 0; i < IA; ++i)
      gld_lds16(Ab + (size_t)i * 64 * lda + k0, As + i * 2048 + t * 8);
#pragma unroll
    for (int i = 0; i < IB; ++i)
      gld_lds16(Bb + (size_t)i * 64 * ldb + k0, Bs + i * 2048 + t * 8);
    asm volatile("s_waitcnt vmcnt(0)" ::: "memory");
    __syncthreads();

    bf16x8 af[WTM], bfv[WTN];
#pragma unroll
    for (int i = 0; i < WTM; ++i)
      af[i] = *(const bf16x8*)(As + (wm * WTM * 16 + i * 16 + fr) * 32 + fk);
#pragma unroll
    for (int j = 0; j < WTN; ++j)
      bfv[j] = *(const bf16x8*)(Bs + (wn * WTN * 16 + j * 16 + fr) * 32 + fk);
#pragma unroll
    for (int i = 0; i < WTM; ++i)
#pragma unroll
      for (int j = 0; j < WTN; ++j)
        acc[i][j] = __builtin_amdgcn_mfma_f32_16x16x32_bf16(af[i], bfv[j],
                                                            acc[i][j], 0, 0, 0);
  }
}

// -------- projection GEMM with fused per-64-chunk L2 normalize --------
// C tile cols are 64-aligned; each wave owns a contiguous 64-col span =
// exactly one head chunk per row. Sum of squares over the 4 j-fragments,
// 16-lane shfl_xor reduce, rsqrt, scale, bf16 store.
__global__ __launch_bounds__(256) void gemm_bt_128_l2n(
    const bf16* __restrict__ A, const bf16* __restrict__ Bt,
    bf16* __restrict__ C, int K, int lda, int ldb, int ldc) {
  __shared__ __align__(16) bf16 As[128 * 32];
  __shared__ __align__(16) bf16 Bs[128 * 32];
  f32x4 acc[4][4] = {};
  const bf16* Ab = A + (size_t)blockIdx.y * 128 * lda;
  const bf16* Bb = Bt + (size_t)blockIdx.x * 128 * ldb;
  gemm_core<2, 2, 4, 4>(Ab, Bb, K, lda, ldb, As, Bs, acc);

  const int t = threadIdx.x, lane = t & 63, wave = t >> 6;
  const int wm = wave & 1, wn = wave >> 1;
  const int cr = (lane >> 4) * 4, cc = lane & 15;
  const size_t row0 = (size_t)blockIdx.y * 128 + wm * 64;
  const size_t col0 = (size_t)blockIdx.x * 128 + wn * 64;
#pragma unroll
  for (int i = 0; i < 4; ++i)
#pragma unroll
    for (int rg = 0; rg < 4; ++rg) {
      float ss = 0.0f;
#pragma unroll
      for (int j = 0; j < 4; ++j) ss += acc[i][j][rg] * acc[i][j][rg];
      ss += __shfl_xor(ss, 1);
      ss += __shfl_xor(ss, 2);
      ss += __shfl_xor(ss, 4);
      ss += __shfl_xor(ss, 8);
      const float r = (ss > 0.0f) ? rsqrtf(ss) : 0.0f;
#pragma unroll
      for (int j = 0; j < 4; ++j)
        C[(row0 + i * 16 + cr + rg) * ldc + col0 + j * 16 + cc] =
            (bf16)(acc[i][j][rg] * r);
    }
}

// -------- final GEMM: C(f32) = A*Bt^T + resid(f32), streaming stores ----
__global__ __launch_bounds__(256) void gemm_bt_resid(
    const bf16* __restrict__ A, const bf16* __restrict__ Bt,
    const float* __restrict__ resid, float* __restrict__ C, int K, int lda,
    int ldb, int ldc) {
  __shared__ __align__(16) bf16 As[128 * 32];
  __shared__ __align__(16) bf16 Bs[128 * 32];
  f32x4 acc[4][4] = {};
  const bf16* Ab = A + (size_t)blockIdx.y * 128 * lda;
  const bf16* Bb = Bt + (size_t)blockIdx.x * 128 * ldb;
  gemm_core<2, 2, 4, 4>(Ab, Bb, K, lda, ldb, As, Bs, acc);

  const int t = threadIdx.x, lane = t & 63, wave = t >> 6;
  const int wm = wave & 1, wn = wave >> 1;
  const int cr = (lane >> 4) * 4, cc = lane & 15;
  const size_t row0 = (size_t)blockIdx.y * 128 + wm * 64;
  const size_t col0 = (size_t)blockIdx.x * 128 + wn * 64;
#pragma unroll
  for (int i = 0; i < 4; ++i)
#pragma unroll
    for (int j = 0; j < 4; ++j)
#pragma unroll
      for (int rg = 0; rg < 4; ++rg) {
        size_t idx = (row0 + i * 16 + cr + rg) * ldc + col0 + j * 16 + cc;
        float rv = __builtin_nontemporal_load(resid + idx);
        __builtin_nontemporal_store(acc[i][j][rg] + rv, C + idx);
      }
}

// =====================================================================
// Pass A: denom[b,h,q] = sum over (m, lk) of mask * exp(S-1).
// Grid (qtile=4, z=256). Q-tile staged once (XOR-swizzled LDS), 8 KV
// tiles streamed with double-buffered K. Row sums accumulate in regs;
// one atomicAdd per row at the end.
// =====================================================================
__global__ __launch_bounds__(256) void denom_kernel(
    const bf16* __restrict__ qh, const bf16* __restrict__ qih,
    const int* __restrict__ mask, float* __restrict__ denom) {
  __shared__ __align__(16) bf16 Qs[128 * 64];
  __shared__ __align__(16) bf16 Ks[2][64 * 64];

  const int z = blockIdx.y;  // (b*M+m)*H + h
  const int bm = z >> 4, h = z & 15;
  const int q0 = blockIdx.x * 128;

  const int t = threadIdx.x;
  const int lane = t & 63;
  const int wave = t >> 6;
  const int wm = wave & 1, wn = wave >> 1;
  const int fr = lane & 15;
  const int hi = lane >> 4;
  const int sr = t >> 3;   // staging row within round (0..31)
  const int sc = t & 7;    // staging 16B chunk (0..7)

  const bf16* qh_b = qh + ((size_t)bm * Lseq + q0) * Dmod + h * DHq;
  const bf16* qih_b = qih + (size_t)bm * Lseq * Dmod + h * DHq;
  const int* mrow = mask + (size_t)bm * Lseq * Lseq;

  // stage Qs (swizzled source cols -> linear LDS; read applies same XOR)
#pragma unroll
  for (int s = 0; s < 4; ++s) {
    const int r = s * 32 + sr;
    gld_lds16(qh_b + (size_t)r * Dmod + ((sc ^ (r & 7)) << 3),
              Qs + s * 2048 + t * 8);
  }
#pragma unroll
  for (int s = 0; s < 2; ++s) {
    const int r = s * 32 + sr;
    gld_lds16(qih_b + (size_t)r * Dmod + ((sc ^ (r & 7)) << 3),
              Ks[0] + s * 2048 + t * 8);
  }

  float racc[4][4] = {};  // per-(i,rg) row partial sums (this lane's cols)

  for (int kt = 0; kt < 8; ++kt) {
    asm volatile("s_waitcnt vmcnt(0)" ::: "memory");
    __syncthreads();
    const bf16* Kc = Ks[kt & 1];

    f32x4 acc_s[4][2] = {};
    __builtin_amdgcn_s_setprio(1);
#pragma unroll
    for (int kk = 0; kk < 2; ++kk) {
      bf16x8 bq[4], bk[2];
#pragma unroll
      for (int i = 0; i < 4; ++i) {
        const int row = wm * 64 + i * 16 + fr;
        bq[i] = *(const bf16x8*)(Qs + row * 64 +
                                 ((((kk << 2) + hi) ^ (row & 7)) << 3));
      }
#pragma unroll
      for (int j = 0; j < 2; ++j) {
        const int row = wn * 32 + j * 16 + fr;
        bk[j] = *(const bf16x8*)(Kc + row * 64 +
                                 ((((kk << 2) + hi) ^ (row & 7)) << 3));
      }
#pragma unroll
      for (int i = 0; i < 4; ++i)
#pragma unroll
        for (int j = 0; j < 2; ++j)
          acc_s[i][j] = __builtin_amdgcn_mfma_f32_16x16x32_bf16(
              bq[i], bk[j], acc_s[i][j], 0, 0, 0);
    }
    __builtin_amdgcn_s_setprio(0);

    if (kt < 7) {  // stage next K tile into the other buffer (no barrier:
                   // writes do not touch the buffer being read)
      const int kv1 = (kt + 1) * 64;
#pragma unroll
      for (int s = 0; s < 2; ++s) {
        const int r = s * 32 + sr;
        gld_lds16(qih_b + (size_t)(kv1 + r) * Dmod + ((sc ^ (r & 7)) << 3),
                  Ks[(kt + 1) & 1] + s * 2048 + t * 8);
      }
    }

    const int kv0 = kt * 64;
#pragma unroll
    for (int i = 0; i < 4; ++i)
#pragma unroll
      for (int j = 0; j < 2; ++j)
#pragma unroll
        for (int rg = 0; rg < 4; ++rg) {
          const int qg = q0 + wm * 64 + i * 16 + hi * 4 + rg;
          const int cg = kv0 + wn * 32 + j * 16 + fr;
          if (mrow[(size_t)qg * Lseq + cg] != 0)
            racc[i][rg] += __expf(acc_s[i][j][rg] - 1.0f);
        }
  }

  // reduce across the 16 column-lanes and atomically add per row
  float* dp = denom + ((size_t)(bm >> 2) * Hq + h) * Lseq + q0 + wm * 64;
#pragma unroll
  for (int i = 0; i < 4; ++i)
#pragma unroll
    for (int rg = 0; rg < 4; ++rg) {
      float rs = racc[i][rg];
      rs += __shfl_xor(rs, 1);
      rs += __shfl_xor(rs, 2);
      rs += __shfl_xor(rs, 4);
      rs += __shfl_xor(rs, 8);
      if (fr == 0) atomicAdd(dp + i * 16 + hi * 4 + rg, rs);
    }
}

// =====================================================================
// Pass B: recompute S tile-by-tile, normalize with precomputed 1/denom,
// write final attn f32 ONCE (non-temporal), bounce normalized P through
// swizzled LDS into MFMA A-fragments, accumulate PV. Grid (qtile=4, z=256).
// LDS: Qs 16K + Ks 8K + Vs 2x8K + Ps 16K = 56 KB -> 2 blocks/CU.
// =====================================================================
__global__ __launch_bounds__(256) void fused_attn(
    const bf16* __restrict__ qh, const bf16* __restrict__ qih,
    const bf16* __restrict__ qih_t, const int* __restrict__ mask,
    const float* __restrict__ denom, float* __restrict__ attn,
    bf16* __restrict__ outh) {
  __shared__ __align__(16) bf16 Qs[128 * 64];
  __shared__ __align__(16) bf16 Ks[64 * 64];
  __shared__ __align__(16) bf16 Vs[2][64 * 64];
  __shared__ __align__(16) bf16 Ps[128 * 64];

  const int z = blockIdx.y;
  const int bm = z >> 4, h = z & 15;
  const int q0 = blockIdx.x * 128;

  const int t = threadIdx.x;
  const int lane = t & 63;
  const int wave = t >> 6;
  const int wm = wave & 1, wn = wave >> 1;
  const int fr = lane & 15;
  const int hi = lane >> 4;
  const int sr = t >> 3;
  const int sc = t & 7;

  const bf16* qh_b = qh + ((size_t)bm * Lseq + q0) * Dmod + h * DHq;
  const bf16* qih_b = qih + (size_t)bm * Lseq * Dmod + h * DHq;
  const bf16* vt_b = qih_t + (size_t)z * DHq * Lseq;
  const int* mrow = mask + (size_t)bm * Lseq * Lseq;
  float* arow = attn + (size_t)z * Lseq * Lseq;

  // stage Qs (resident for whole kernel)
#pragma unroll
  for (int s = 0; s < 4; ++s) {
    const int r = s * 32 + sr;
    gld_lds16(qh_b + (size_t)r * Dmod + ((sc ^ (r & 7)) << 3),
              Qs + s * 2048 + t * 8);
  }
  // prologue staging of K(0), V(0)
#pragma unroll
  for (int s = 0; s < 2; ++s) {
    const int r = s * 32 + sr;
    gld_lds16(qih_b + (size_t)r * Dmod + ((sc ^ (r & 7)) << 3),
              Ks + s * 2048 + t * 8);
    gld_lds16(vt_b + (size_t)r * Lseq + ((sc ^ (r & 7)) << 3),
              Vs[0] + s * 2048 + t * 8);
  }

  // 1/denom for this lane's 16 rows (L1/L2 hits; 128 KB buffer)
  const float* drow = denom + ((size_t)(bm >> 2) * Hq + h) * Lseq + q0;
  float invd[4][4];
#pragma unroll
  for (int i = 0; i < 4; ++i)
#pragma unroll
    for (int rg = 0; rg < 4; ++rg) {
      const float d = drow[wm * 64 + i * 16 + hi * 4 + rg];
      invd[i][rg] = (d > 0.0f) ? 1.0f / d : 0.0f;
    }

  f32x4 acc_o[4][2] = {};

  for (int kt = 0; kt < 8; ++kt) {
    const int kv0 = kt * 64;
    asm volatile("s_waitcnt vmcnt(0)" ::: "memory");
    __syncthreads();  // K(kt), V(kt) ready; Ps free (barrier after last PV)

    // ---- QK^T: S[128,64], wave tile 64 x 32 ----
    f32x4 acc_s[4][2] = {};
    __builtin_amdgcn_s_setprio(1);
#pragma unroll
    for (int kk = 0; kk < 2; ++kk) {
      bf16x8 bq[4], bk[2];
#pragma unroll
      for (int i = 0; i < 4; ++i) {
        const int row = wm * 64 + i * 16 + fr;
        bq[i] = *(const bf16x8*)(Qs + row * 64 +
                                 ((((kk << 2) + hi) ^ (row & 7)) << 3));
      }
#pragma unroll
      for (int j = 0; j < 2; ++j) {
        const int row = wn * 32 + j * 16 + fr;
        bk[j] = *(const bf16x8*)(Ks + row * 64 +
                                 ((((kk << 2) + hi) ^ (row & 7)) << 3));
      }
#pragma unroll
      for (int i = 0; i < 4; ++i)
#pragma unroll
        for (int j = 0; j < 2; ++j)
          acc_s[i][j] = __builtin_amdgcn_mfma_f32_16x16x32_bf16(
              bq[i], bk[j], acc_s[i][j], 0, 0, 0);
    }
    __builtin_amdgcn_s_setprio(0);
    __syncthreads();  // all waves done reading Ks -> safe to restage

    // issue next-tile staging early; completes under epilogue+PV
    if (kt < 7) {
      const int kv1 = kv0 + 64;
#pragma unroll
      for (int s = 0; s < 2; ++s) {
        const int r = s * 32 + sr;
        gld_lds16(qih_b + (size_t)(kv1 + r) * Dmod + ((sc ^ (r & 7)) << 3),
                  Ks + s * 2048 + t * 8);
        gld_lds16(vt_b + (size_t)r * Lseq + kv1 + ((sc ^ (r & 7)) << 3),
                  Vs[(kt + 1) & 1] + s * 2048 + t * 8);
      }
    }

    // ---- epilogue: mask, exp, normalize, write attn (NT), write Ps ----
#pragma unroll
    for (int i = 0; i < 4; ++i)
#pragma unroll
      for (int j = 0; j < 2; ++j)
#pragma unroll
        for (int rg = 0; rg < 4; ++rg) {
          const int ql = wm * 64 + i * 16 + hi * 4 + rg;
          const int cl = wn * 32 + j * 16 + fr;
          const int qg = q0 + ql;
          const int cg = kv0 + cl;
          float p = 0.0f;
          if (mrow[(size_t)qg * Lseq + cg] != 0)
            p = __expf(acc_s[i][j][rg] - 1.0f) * invd[i][rg];
          __builtin_nontemporal_store(p, arow + (size_t)qg * Lseq + cg);
          Ps[ql * 64 + (((cl >> 3) ^ (ql & 7)) << 3) + (cl & 7)] = (bf16)p;
        }
    __syncthreads();  // Ps complete (cross-wave read next)

    // ---- PV: acc_o += P[128,64] * V^T (Vs = qih_t tile [dh][lk]) ----
    const bf16* Vc = Vs[kt & 1];
    __builtin_amdgcn_s_setprio(1);
#pragma unroll
    for (int kk = 0; kk < 2; ++kk) {
      bf16x8 ap[4], bv[2];
#pragma unroll
      for (int i = 0; i < 4; ++i) {
        const int row = wm * 64 + i * 16 + fr;
        ap[i] = *(const bf16x8*)(Ps + row * 64 +
                                 ((((kk << 2) + hi) ^ (row & 7)) << 3));
      }
#pragma unroll
      for (int j = 0; j < 2; ++j) {
        const int row = wn * 32 + j * 16 + fr;
        bv[j] = *(const bf16x8*)(Vc + row * 64 +
                                 ((((kk << 2) + hi) ^ (row & 7)) << 3));
      }
#pragma unroll
      for (int i = 0; i < 4; ++i)
#pragma unroll
        for (int j = 0; j < 2; ++j)
          acc_o[i][j] = __builtin_amdgcn_mfma_f32_16x16x32_bf16(
              ap[i], bv[j], acc_o[i][j], 0, 0, 0);
    }
    __builtin_amdgcn_s_setprio(0);
    __syncthreads();  // Ps/V consumed before next epilogue/staging cycle
  }

  // write outh tile [128 x 64] (head h's column span)
  bf16* Cb = outh + ((size_t)bm * Lseq + q0) * Dmod + h * DHq;
#pragma unroll
  for (int i = 0; i < 4; ++i)
#pragma unroll
    for (int j = 0; j < 2; ++j)
#pragma unroll
      for (int rg = 0; rg < 4; ++rg)
        Cb[(size_t)(wm * 64 + i * 16 + hi * 4 + rg) * Dmod + wn * 32 +
           j * 16 + fr] = (bf16)acc_o[i][j][rg];
}

// -------- LayerNorm over D=1024, f32 in -> bf16 out, one block/row -------
__global__ __launch_bounds__(256) void ln_kernel(const float* __restrict__ q,
                                                 const float* __restrict__ g,
                                                 const float* __restrict__ b,
                                                 bf16* __restrict__ qn) {
  const size_t row = blockIdx.x;
  const float* x = q + row * Dmod;
  bf16* y = qn + row * Dmod;
  const int t = threadIdx.x;
  float4 v = *(const float4*)(x + t * 4);
  float s = v.x + v.y + v.z + v.w;
  float ss = v.x * v.x + v.y * v.y + v.z * v.z + v.w * v.w;
  for (int off = 32; off; off >>= 1) {
    s += __shfl_xor(s, off);
    ss += __shfl_xor(ss, off);
  }
  __shared__ float sm[8];
  const int wave = t >> 6, lane = t & 63;
  if (lane == 0) { sm[wave * 2] = s; sm[wave * 2 + 1] = ss; }
  __syncthreads();
  s = sm[0] + sm[2] + sm[4] + sm[6];
  ss = sm[1] + sm[3] + sm[5] + sm[7];
  const float mean = s * (1.0f / Dmod);
  const float var = ss * (1.0f / Dmod) - mean * mean;
  const float rstd = rsqrtf(var + 1e-6f);
  float4 gg = *(const float4*)(g + t * 4);
  float4 bb = *(const float4*)(b + t * 4);
  bf16x4 o;
  o[0] = (bf16)((v.x - mean) * rstd * gg.x + bb.x);
  o[1] = (bf16)((v.y - mean) * rstd * gg.y + bb.y);
  o[2] = (bf16)((v.z - mean) * rstd * gg.z + bb.z);
  o[3] = (bf16)((v.w - mean) * rstd * gg.w + bb.w);
  *(bf16x4*)(y + t * 4) = o;
}

// -------- f32 -> bf16 bulk convert (for qi) --------
__global__ __launch_bounds__(256) void cvt_f32_bf16(const float* __restrict__ in,
                                                    bf16* __restrict__ out) {
  const size_t i = ((size_t)blockIdx.x * 256 + threadIdx.x) * 4;
  float4 v = *(const float4*)(in + i);
  bf16x4 o;
  o[0] = (bf16)v.x; o[1] = (bf16)v.y; o[2] = (bf16)v.z; o[3] = (bf16)v.w;
  *(bf16x4*)(out + i) = o;
}

// -------- 64x64 tiled transpose, f32 in -> bf16 out ------
__global__ __launch_bounds__(256) void transpose64_f32(
    const float* __restrict__ in, bf16* __restrict__ out, int ld_in,
    int ld_out) {
  __shared__ bf16 tile[64 * 65];
  const int r0 = blockIdx.y * 64, c0 = blockIdx.x * 64;
  const int t = threadIdx.x, cl = t & 63, rq = t >> 6;
#pragma unroll
  for (int it = 0; it < 16; ++it) {
    const int rl = it * 4 + rq;
    tile[cl * 65 + rl] = (bf16)in[(size_t)(r0 + rl) * ld_in + c0 + cl];
  }
  __syncthreads();
#pragma unroll
  for (int it = 0; it < 16; ++it) {
    const int ol = it * 4 + rq;
    out[(size_t)(c0 + ol) * ld_out + r0 + cl] = tile[ol * 65 + cl];
  }
}

// -------- per-(b,m,h) transpose of qih [512,64]->[64,512] for PV Bt ------
__global__ __launch_bounds__(256) void transpose_qih(
    const bf16* __restrict__ qih, bf16* __restrict__ qih_t) {
  __shared__ bf16 tile[64 * 65];
  const int z = blockIdx.z;
  const int bm = z >> 4, h = z & 15;
  const bf16* in = qih + (size_t)bm * Lseq * Dmod + h * DHq;  // 512x64 ld 1024
  bf16* out = qih_t + (size_t)z * DHq * Lseq;                 // 64x512 ld 512
  const int r0 = blockIdx.x * 64;  // lk tile
  const int t = threadIdx.x, cl = t & 63, rq = t >> 6;
#pragma unroll
  for (int it = 0; it < 16; ++it) {
    const int rl = it * 4 + rq;
    tile[cl * 65 + rl] = in[(size_t)(r0 + rl) * Dmod + cl];
  }
  __syncthreads();
#pragma unroll
  for (int it = 0; it < 16; ++it) {
    const int dh = it * 4 + rq;
    out[(size_t)dh * Lseq + r0 + cl] = tile[dh * 65 + cl];
  }
}

extern "C" void kernel_launch(void* const* d_in, const int* in_sizes, int n_in,
                              void* d_out, int out_size, void* d_ws,
                              size_t ws_size, hipStream_t stream) {
  const float* q = (const float*)d_in[0];
  // d_in[1] = k, unused by the reference forward
  const float* qi = (const float*)d_in[2];
  const int* mask = (const int*)d_in[3];
  const float* w_qs = (const float*)d_in[4];
  const float* w_qis = (const float*)d_in[5];
  const float* w_fc = (const float*)d_in[6];
  const float* ln_g = (const float*)d_in[7];
  const float* ln_b = (const float*)d_in[8];

  float* out = (float*)d_out;
  const size_t NE = (size_t)Bq * Mq * Lseq * Dmod;  // 8,388,608
  float* attn = out + NE;  // second tuple element (67,108,864 f32)

  // Scratch parked in the attn output region (dead before fused_attn):
  char* attnc = (char*)attn;  // 268 MB available
  bf16* qib = (bf16*)attnc;                       // 16 MB
  bf16* wqs_t = (bf16*)(attnc + (16u << 20));     // 2 MB
  bf16* wqis_t = (bf16*)(attnc + (18u << 20));    // 2 MB

  char* ws = (char*)d_ws;
  const size_t SZ = NE * sizeof(bf16);  // 16 MiB
  bf16* qn = (bf16*)(ws);               // LN out; reused as out_h later
  bf16* qh = (bf16*)(ws + SZ);
  bf16* qih = (bf16*)(ws + 2 * SZ);
  bf16* qih_t = (bf16*)(ws + 3 * SZ);
  bf16* wfc_t = (bf16*)(ws + 4 * SZ);   // must survive to the last GEMM
  float* denom = (float*)(ws + 4 * SZ + (2u << 20));  // [B,H,L] = 128 KB
  bf16* outh = qn;                      // qn dead after first projection

  const int ROWS = Bq * Mq * Lseq;  // 8192

  // 1) input conversions / weight transposes (Bt layout for gemm core)
  cvt_f32_bf16<<<NE / 1024, 256, 0, stream>>>(qi, qib);
  transpose64_f32<<<dim3(16, 16), 256, 0, stream>>>(w_qs, wqs_t, Dmod, Dmod);
  transpose64_f32<<<dim3(16, 16), 256, 0, stream>>>(w_qis, wqis_t, Dmod, Dmod);
  transpose64_f32<<<dim3(16, 16), 256, 0, stream>>>(w_fc, wfc_t, Dmod, Dmod);
  hipMemsetAsync(denom, 0, (size_t)Bq * Hq * Lseq * sizeof(float), stream);

  // 2) LayerNorm(q) -> qn
  ln_kernel<<<ROWS, 256, 0, stream>>>(q, ln_g, ln_b, qn);

  // 3) projections with fused per-head L2 normalize
  gemm_bt_128_l2n<<<dim3(Dmod / 128, ROWS / 128), 256, 0, stream>>>(
      qn, wqs_t, qh, Dmod, Dmod, Dmod, Dmod);
  gemm_bt_128_l2n<<<dim3(Dmod / 128, ROWS / 128), 256, 0, stream>>>(
      qib, wqis_t, qih, Dmod, Dmod, Dmod, Dmod);

  // 4) qih^T per (b,m,h) for the PV operand
  transpose_qih<<<dim3(Lseq / 64, 1, Bq * Mq * Hq), 256, 0, stream>>>(qih,
                                                                      qih_t);

  // 5) Pass A: softmax denominators (no P store)
  denom_kernel<<<dim3(Lseq / 128, Bq * Mq * Hq), 256, 0, stream>>>(
      qh, qih, mask, denom);

  // 6) Pass B: recompute S, normalize, write attn once, fused PV
  fused_attn<<<dim3(Lseq / 128, Bq * Mq * Hq), 256, 0, stream>>>(
      qh, qih, qih_t, mask, denom, attn, outh);

  // 7) out = out_h @ w_fc + q (f32 out, f32 residual)
  gemm_bt_resid<<<dim3(Dmod / 128, ROWS / 128), 256, 0, stream>>>(
      outh, wfc_t, q, out, Dmod, Dmod, Dmod, Dmod);
}

// Round 5
// 600.538 us; speedup vs baseline: 1.2274x; 1.0251x over previous
//
#include <hip/hip_runtime.h>
#include <hip/hip_bf16.h>
#include <cstdint>
#include <cstddef>

// Problem constants
#define Bq 4
#define Mq 4
#define Lseq 512
#define Dmod 1024
#define Hq 16
#define DHq 64

using bf16 = __bf16;
using bf16x4 = __attribute__((ext_vector_type(4))) __bf16;
using bf16x8 = __attribute__((ext_vector_type(8))) __bf16;
using f32x4 = __attribute__((ext_vector_type(4))) float;
using u64 = unsigned long long;

// -------- async global->LDS, 16B per lane (m97 pattern) --------
__device__ __forceinline__ void gld_lds16(const bf16* g, bf16* l) {
  __builtin_amdgcn_global_load_lds(
      (const __attribute__((address_space(1))) void*)g,
      (__attribute__((address_space(3))) void*)l, 16, 0, 0);
}

// =====================================================================
// GEMM core: C[BM,BN] = A[BM,K] * Bt[BN,K]^T, bf16 in, f32 accum.
// =====================================================================
template <int WAVES_M, int WAVES_N, int WTM, int WTN>
__device__ __forceinline__ void gemm_core(const bf16* __restrict__ A,
                                          const bf16* __restrict__ Bt,
                                          int K, int lda, int ldb,
                                          bf16* As, bf16* Bs,
                                          f32x4 (&acc)[WTM][WTN]) {
  constexpr int BM = WAVES_M * WTM * 16;
  constexpr int BN = WAVES_N * WTN * 16;
  constexpr int IA = BM / 64;
  constexpr int IB = BN / 64;

  const int t = threadIdx.x;
  const int lane = t & 63;
  const int wave = t >> 6;
  const int wm = wave % WAVES_M;
  const int wn = wave / WAVES_M;
  const int r = t >> 2;            // staging row (0..63)
  const int c8 = (t & 3) * 8;      // staging col (bf16 elems)
  const int fr = lane & 15;        // fragment row/col within 16-tile
  const int fk = (lane >> 4) * 8;  // fragment k offset

  const bf16* Ab = A + (size_t)r * lda + c8;
  const bf16* Bb = Bt + (size_t)r * ldb + c8;

  for (int k0 = 0; k0 < K; k0 += 32) {
    if (k0) __syncthreads();  // protect LDS from previous iter's readers
#pragma unroll
    for (int i = 0; i < IA; ++i)
      gld_lds16(Ab + (size_t)i * 64 * lda + k0, As + i * 2048 + t * 8);
#pragma unroll
    for (int i = 0; i < IB; ++i)
      gld_lds16(Bb + (size_t)i * 64 * ldb + k0, Bs + i * 2048 + t * 8);
    asm volatile("s_waitcnt vmcnt(0)" ::: "memory");
    __syncthreads();

    bf16x8 af[WTM], bfv[WTN];
#pragma unroll
    for (int i = 0; i < WTM; ++i)
      af[i] = *(const bf16x8*)(As + (wm * WTM * 16 + i * 16 + fr) * 32 + fk);
#pragma unroll
    for (int j = 0; j < WTN; ++j)
      bfv[j] = *(const bf16x8*)(Bs + (wn * WTN * 16 + j * 16 + fr) * 32 + fk);
#pragma unroll
    for (int i = 0; i < WTM; ++i)
#pragma unroll
      for (int j = 0; j < WTN; ++j)
        acc[i][j] = __builtin_amdgcn_mfma_f32_16x16x32_bf16(af[i], bfv[j],
                                                            acc[i][j], 0, 0, 0);
  }
}

// -------- projection GEMM with fused per-64-chunk L2 normalize --------
__global__ __launch_bounds__(256) void gemm_bt_128_l2n(
    const bf16* __restrict__ A, const bf16* __restrict__ Bt,
    bf16* __restrict__ C, int K, int lda, int ldb, int ldc) {
  __shared__ __align__(16) bf16 As[128 * 32];
  __shared__ __align__(16) bf16 Bs[128 * 32];
  f32x4 acc[4][4] = {};
  const bf16* Ab = A + (size_t)blockIdx.y * 128 * lda;
  const bf16* Bb = Bt + (size_t)blockIdx.x * 128 * ldb;
  gemm_core<2, 2, 4, 4>(Ab, Bb, K, lda, ldb, As, Bs, acc);

  const int t = threadIdx.x, lane = t & 63, wave = t >> 6;
  const int wm = wave & 1, wn = wave >> 1;
  const int cr = (lane >> 4) * 4, cc = lane & 15;
  const size_t row0 = (size_t)blockIdx.y * 128 + wm * 64;
  const size_t col0 = (size_t)blockIdx.x * 128 + wn * 64;
#pragma unroll
  for (int i = 0; i < 4; ++i)
#pragma unroll
    for (int rg = 0; rg < 4; ++rg) {
      float ss = 0.0f;
#pragma unroll
      for (int j = 0; j < 4; ++j) ss += acc[i][j][rg] * acc[i][j][rg];
      ss += __shfl_xor(ss, 1);
      ss += __shfl_xor(ss, 2);
      ss += __shfl_xor(ss, 4);
      ss += __shfl_xor(ss, 8);
      const float r = (ss > 0.0f) ? rsqrtf(ss) : 0.0f;
#pragma unroll
      for (int j = 0; j < 4; ++j)
        C[(row0 + i * 16 + cr + rg) * ldc + col0 + j * 16 + cc] =
            (bf16)(acc[i][j][rg] * r);
    }
}

// -------- final GEMM: C(f32) = A*Bt^T + resid(f32), streaming stores ----
__global__ __launch_bounds__(256) void gemm_bt_resid(
    const bf16* __restrict__ A, const bf16* __restrict__ Bt,
    const float* __restrict__ resid, float* __restrict__ C, int K, int lda,
    int ldb, int ldc) {
  __shared__ __align__(16) bf16 As[128 * 32];
  __shared__ __align__(16) bf16 Bs[128 * 32];
  f32x4 acc[4][4] = {};
  const bf16* Ab = A + (size_t)blockIdx.y * 128 * lda;
  const bf16* Bb = Bt + (size_t)blockIdx.x * 128 * ldb;
  gemm_core<2, 2, 4, 4>(Ab, Bb, K, lda, ldb, As, Bs, acc);

  const int t = threadIdx.x, lane = t & 63, wave = t >> 6;
  const int wm = wave & 1, wn = wave >> 1;
  const int cr = (lane >> 4) * 4, cc = lane & 15;
  const size_t row0 = (size_t)blockIdx.y * 128 + wm * 64;
  const size_t col0 = (size_t)blockIdx.x * 128 + wn * 64;
#pragma unroll
  for (int i = 0; i < 4; ++i)
#pragma unroll
    for (int j = 0; j < 4; ++j)
#pragma unroll
      for (int rg = 0; rg < 4; ++rg) {
        size_t idx = (row0 + i * 16 + cr + rg) * ldc + col0 + j * 16 + cc;
        float rv = __builtin_nontemporal_load(resid + idx);
        __builtin_nontemporal_store(acc[i][j][rg] + rv, C + idx);
      }
}

// -------- mask [B,M,L,L] int32 -> bitmask [B,M,L,8] u64 (ballot) --------
__global__ __launch_bounds__(256) void mask_to_bits(
    const int* __restrict__ mask, u64* __restrict__ mb) {
  const int wid = blockIdx.x * 4 + (threadIdx.x >> 6);  // 0..4095
  const int lane = threadIdx.x & 63;
#pragma unroll
  for (int it = 0; it < 16; ++it) {
    const size_t W = (size_t)wid * 16 + it;  // 65536 words total
    const u64 b = __ballot(mask[W * 64 + lane] != 0);
    if (lane == 0) mb[W] = b;
  }
}

// block-index swizzle: each XCD owns 32 consecutive z (2 bm x 16 heads);
// the 4 qtile-siblings of a z dispatch adjacently on the same XCD.
__device__ __forceinline__ void attn_swizzle(int flat, int& z, int& q0) {
  const int slot = flat >> 3;
  z = (flat & 7) * 32 + (slot >> 2);
  q0 = (slot & 3) * 128;
}

// =====================================================================
// Pass A: denom[b,h,q] = sum over (m, lk) of mask * exp(S-1).
// 1024 blocks (swizzled). Q resident; K double-buffered, staged BEFORE
// QK^T so the prefetch spans compute. Bitmask words hoisted pre-MFMA.
// =====================================================================
__global__ __launch_bounds__(256) void denom_kernel(
    const bf16* __restrict__ qh, const bf16* __restrict__ qih,
    const u64* __restrict__ mb, float* __restrict__ denom) {
  __shared__ __align__(16) bf16 Qs[128 * 64];
  __shared__ __align__(16) bf16 Ks[2][64 * 64];

  int z, q0;
  attn_swizzle(blockIdx.x, z, q0);
  const int bm = z >> 4, h = z & 15;

  const int t = threadIdx.x;
  const int lane = t & 63;
  const int wave = t >> 6;
  const int wm = wave & 1, wn = wave >> 1;
  const int fr = lane & 15;
  const int hi = lane >> 4;
  const int sr = t >> 3;   // staging row within round (0..31)
  const int sc = t & 7;    // staging 16B chunk (0..7)

  const bf16* qh_b = qh + ((size_t)bm * Lseq + q0) * Dmod + h * DHq;
  const bf16* qih_b = qih + (size_t)bm * Lseq * Dmod + h * DHq;
  const u64* mrow = mb + (size_t)bm * Lseq * 8;

  // stage Qs (swizzled source cols -> linear LDS; read applies same XOR)
#pragma unroll
  for (int s = 0; s < 4; ++s) {
    const int r = s * 32 + sr;
    gld_lds16(qh_b + (size_t)r * Dmod + ((sc ^ (r & 7)) << 3),
              Qs + s * 2048 + t * 8);
  }
#pragma unroll
  for (int s = 0; s < 2; ++s) {
    const int r = s * 32 + sr;
    gld_lds16(qih_b + (size_t)r * Dmod + ((sc ^ (r & 7)) << 3),
              Ks[0] + s * 2048 + t * 8);
  }

  float racc[4][4] = {};  // per-(i,rg) row partial sums (this lane's cols)

  for (int kt = 0; kt < 8; ++kt) {
    asm volatile("s_waitcnt vmcnt(0)" ::: "memory");
    __syncthreads();

    // prefetch next K tile FIRST (covered by QK^T + epilogue)
    if (kt < 7) {
      const int kv1 = (kt + 1) * 64;
#pragma unroll
      for (int s = 0; s < 2; ++s) {
        const int r = s * 32 + sr;
        gld_lds16(qih_b + (size_t)(kv1 + r) * Dmod + ((sc ^ (r & 7)) << 3),
                  Ks[(kt + 1) & 1] + s * 2048 + t * 8);
      }
    }

    // bitmask words for this kt window (broadcast loads, retire under MFMA)
    u64 mw[4][4];
#pragma unroll
    for (int i = 0; i < 4; ++i)
#pragma unroll
      for (int rg = 0; rg < 4; ++rg)
        mw[i][rg] =
            mrow[(size_t)(q0 + wm * 64 + i * 16 + hi * 4 + rg) * 8 + kt];

    const bf16* Kc = Ks[kt & 1];
    f32x4 acc_s[4][2] = {};
    __builtin_amdgcn_s_setprio(1);
#pragma unroll
    for (int kk = 0; kk < 2; ++kk) {
      bf16x8 bq[4], bk[2];
#pragma unroll
      for (int i = 0; i < 4; ++i) {
        const int row = wm * 64 + i * 16 + fr;
        bq[i] = *(const bf16x8*)(Qs + row * 64 +
                                 ((((kk << 2) + hi) ^ (row & 7)) << 3));
      }
#pragma unroll
      for (int j = 0; j < 2; ++j) {
        const int row = wn * 32 + j * 16 + fr;
        bk[j] = *(const bf16x8*)(Kc + row * 64 +
                                 ((((kk << 2) + hi) ^ (row & 7)) << 3));
      }
#pragma unroll
      for (int i = 0; i < 4; ++i)
#pragma unroll
        for (int j = 0; j < 2; ++j)
          acc_s[i][j] = __builtin_amdgcn_mfma_f32_16x16x32_bf16(
              bq[i], bk[j], acc_s[i][j], 0, 0, 0);
    }
    __builtin_amdgcn_s_setprio(0);

#pragma unroll
    for (int i = 0; i < 4; ++i)
#pragma unroll
      for (int rg = 0; rg < 4; ++rg) {
        const unsigned hw = (unsigned)(mw[i][rg] >> (wn * 32));
#pragma unroll
        for (int j = 0; j < 2; ++j)
          if ((hw >> (j * 16 + fr)) & 1)
            racc[i][rg] += __expf(acc_s[i][j][rg] - 1.0f);
      }
  }

  // reduce across the 16 column-lanes and atomically add per row
  float* dp = denom + ((size_t)(bm >> 2) * Hq + h) * Lseq + q0 + wm * 64;
#pragma unroll
  for (int i = 0; i < 4; ++i)
#pragma unroll
    for (int rg = 0; rg < 4; ++rg) {
      float rs = racc[i][rg];
      rs += __shfl_xor(rs, 1);
      rs += __shfl_xor(rs, 2);
      rs += __shfl_xor(rs, 4);
      rs += __shfl_xor(rs, 8);
      if (fr == 0) atomicAdd(dp + i * 16 + hi * 4 + rg, rs);
    }
}

// =====================================================================
// Pass B: recompute S, normalize with 1/denom, write attn f32 once (NT),
// bounce P through swizzled LDS, fused PV. Fully double-buffered
// (Ks[2],Vs[2],Ps[2] -> 80 KB, 2 blocks/CU); 2 barriers per kt, the mid
// barrier raw (lgkmcnt only) so K/V prefetch stays in flight across PV.
// =====================================================================
__global__ __launch_bounds__(256) void fused_attn(
    const bf16* __restrict__ qh, const bf16* __restrict__ qih,
    const bf16* __restrict__ qih_t, const u64* __restrict__ mb,
    const float* __restrict__ denom, float* __restrict__ attn,
    bf16* __restrict__ outh) {
  __shared__ __align__(16) bf16 Qs[128 * 64];
  __shared__ __align__(16) bf16 Ks[2][64 * 64];
  __shared__ __align__(16) bf16 Vs[2][64 * 64];
  __shared__ __align__(16) bf16 Ps[2][128 * 64];

  int z, q0;
  attn_swizzle(blockIdx.x, z, q0);
  const int bm = z >> 4, h = z & 15;

  const int t = threadIdx.x;
  const int lane = t & 63;
  const int wave = t >> 6;
  const int wm = wave & 1, wn = wave >> 1;
  const int fr = lane & 15;
  const int hi = lane >> 4;
  const int sr = t >> 3;
  const int sc = t & 7;

  const bf16* qh_b = qh + ((size_t)bm * Lseq + q0) * Dmod + h * DHq;
  const bf16* qih_b = qih + (size_t)bm * Lseq * Dmod + h * DHq;
  const bf16* vt_b = qih_t + (size_t)z * DHq * Lseq;
  const u64* mrow = mb + (size_t)bm * Lseq * 8;
  float* arow = attn + (size_t)z * Lseq * Lseq;

  // stage Qs (resident for whole kernel)
#pragma unroll
  for (int s = 0; s < 4; ++s) {
    const int r = s * 32 + sr;
    gld_lds16(qh_b + (size_t)r * Dmod + ((sc ^ (r & 7)) << 3),
              Qs + s * 2048 + t * 8);
  }
  // prologue staging of K(0), V(0)
#pragma unroll
  for (int s = 0; s < 2; ++s) {
    const int r = s * 32 + sr;
    gld_lds16(qih_b + (size_t)r * Dmod + ((sc ^ (r & 7)) << 3),
              Ks[0] + s * 2048 + t * 8);
    gld_lds16(vt_b + (size_t)r * Lseq + ((sc ^ (r & 7)) << 3),
              Vs[0] + s * 2048 + t * 8);
  }

  // 1/denom for this lane's 16 rows
  const float* drow = denom + ((size_t)(bm >> 2) * Hq + h) * Lseq + q0;
  float invd[4][4];
#pragma unroll
  for (int i = 0; i < 4; ++i)
#pragma unroll
    for (int rg = 0; rg < 4; ++rg) {
      const float d = drow[wm * 64 + i * 16 + hi * 4 + rg];
      invd[i][rg] = (d > 0.0f) ? 1.0f / d : 0.0f;
    }

  f32x4 acc_o[4][2] = {};

  for (int kt = 0; kt < 8; ++kt) {
    const int kv0 = kt * 64;
    asm volatile("s_waitcnt vmcnt(0)" ::: "memory");
    __syncthreads();  // (1) K/V(kt) landed; Ps[kt&1] free (PV kt-2 done)

    // prefetch K/V(kt+1) into the other buffers (spans QK^T+epi+PV)
    if (kt < 7) {
      const int kv1 = kv0 + 64;
#pragma unroll
      for (int s = 0; s < 2; ++s) {
        const int r = s * 32 + sr;
        gld_lds16(qih_b + (size_t)(kv1 + r) * Dmod + ((sc ^ (r & 7)) << 3),
                  Ks[(kt + 1) & 1] + s * 2048 + t * 8);
        gld_lds16(vt_b + (size_t)r * Lseq + kv1 + ((sc ^ (r & 7)) << 3),
                  Vs[(kt + 1) & 1] + s * 2048 + t * 8);
      }
    }

    // bitmask words for this kt window (retire under MFMA)
    u64 mw[4][4];
#pragma unroll
    for (int i = 0; i < 4; ++i)
#pragma unroll
      for (int rg = 0; rg < 4; ++rg)
        mw[i][rg] =
            mrow[(size_t)(q0 + wm * 64 + i * 16 + hi * 4 + rg) * 8 + kt];

    // ---- QK^T: S[128,64], wave tile 64 x 32 ----
    const bf16* Kc = Ks[kt & 1];
    f32x4 acc_s[4][2] = {};
    __builtin_amdgcn_s_setprio(1);
#pragma unroll
    for (int kk = 0; kk < 2; ++kk) {
      bf16x8 bq[4], bk[2];
#pragma unroll
      for (int i = 0; i < 4; ++i) {
        const int row = wm * 64 + i * 16 + fr;
        bq[i] = *(const bf16x8*)(Qs + row * 64 +
                                 ((((kk << 2) + hi) ^ (row & 7)) << 3));
      }
#pragma unroll
      for (int j = 0; j < 2; ++j) {
        const int row = wn * 32 + j * 16 + fr;
        bk[j] = *(const bf16x8*)(Kc + row * 64 +
                                 ((((kk << 2) + hi) ^ (row & 7)) << 3));
      }
#pragma unroll
      for (int i = 0; i < 4; ++i)
#pragma unroll
        for (int j = 0; j < 2; ++j)
          acc_s[i][j] = __builtin_amdgcn_mfma_f32_16x16x32_bf16(
              bq[i], bk[j], acc_s[i][j], 0, 0, 0);
    }
    __builtin_amdgcn_s_setprio(0);

    // ---- epilogue: mask-bit, exp, normalize, write attn (NT), write Ps --
    bf16* Pc = Ps[kt & 1];
#pragma unroll
    for (int i = 0; i < 4; ++i)
#pragma unroll
      for (int j = 0; j < 2; ++j)
#pragma unroll
        for (int rg = 0; rg < 4; ++rg) {
          const int ql = wm * 64 + i * 16 + hi * 4 + rg;
          const int cl = wn * 32 + j * 16 + fr;
          const unsigned hw = (unsigned)(mw[i][rg] >> (wn * 32));
          float p = 0.0f;
          if ((hw >> (j * 16 + fr)) & 1)
            p = __expf(acc_s[i][j][rg] - 1.0f) * invd[i][rg];
          __builtin_nontemporal_store(
              p, arow + (size_t)(q0 + ql) * Lseq + kv0 + cl);
          Pc[ql * 64 + (((cl >> 3) ^ (ql & 7)) << 3) + (cl & 7)] = (bf16)p;
        }
    asm volatile("s_waitcnt lgkmcnt(0)" ::: "memory");
    __builtin_amdgcn_s_barrier();  // (2) raw: staging/NT stores stay in flight

    // ---- PV: acc_o += P[128,64] * V^T (Vs = qih_t tile [dh][lk]) ----
    const bf16* Vc = Vs[kt & 1];
    __builtin_amdgcn_s_setprio(1);
#pragma unroll
    for (int kk = 0; kk < 2; ++kk) {
      bf16x8 ap[4], bv[2];
#pragma unroll
      for (int i = 0; i < 4; ++i) {
        const int row = wm * 64 + i * 16 + fr;
        ap[i] = *(const bf16x8*)(Pc + row * 64 +
                                 ((((kk << 2) + hi) ^ (row & 7)) << 3));
      }
#pragma unroll
      for (int j = 0; j < 2; ++j) {
        const int row = wn * 32 + j * 16 + fr;
        bv[j] = *(const bf16x8*)(Vc + row * 64 +
                                 ((((kk << 2) + hi) ^ (row & 7)) << 3));
      }
#pragma unroll
      for (int i = 0; i < 4; ++i)
#pragma unroll
        for (int j = 0; j < 2; ++j)
          acc_o[i][j] = __builtin_amdgcn_mfma_f32_16x16x32_bf16(
              ap[i], bv[j], acc_o[i][j], 0, 0, 0);
    }
    __builtin_amdgcn_s_setprio(0);
  }

  // write outh tile [128 x 64] (head h's column span)
  bf16* Cb = outh + ((size_t)bm * Lseq + q0) * Dmod + h * DHq;
#pragma unroll
  for (int i = 0; i < 4; ++i)
#pragma unroll
    for (int j = 0; j < 2; ++j)
#pragma unroll
      for (int rg = 0; rg < 4; ++rg)
        Cb[(size_t)(wm * 64 + i * 16 + hi * 4 + rg) * Dmod + wn * 32 +
           j * 16 + fr] = (bf16)acc_o[i][j][rg];
}

// -------- LayerNorm over D=1024, f32 in -> bf16 out, one block/row -------
__global__ __launch_bounds__(256) void ln_kernel(const float* __restrict__ q,
                                                 const float* __restrict__ g,
                                                 const float* __restrict__ b,
                                                 bf16* __restrict__ qn) {
  const size_t row = blockIdx.x;
  const float* x = q + row * Dmod;
  bf16* y = qn + row * Dmod;
  const int t = threadIdx.x;
  float4 v = *(const float4*)(x + t * 4);
  float s = v.x + v.y + v.z + v.w;
  float ss = v.x * v.x + v.y * v.y + v.z * v.z + v.w * v.w;
  for (int off = 32; off; off >>= 1) {
    s += __shfl_xor(s, off);
    ss += __shfl_xor(ss, off);
  }
  __shared__ float sm[8];
  const int wave = t >> 6, lane = t & 63;
  if (lane == 0) { sm[wave * 2] = s; sm[wave * 2 + 1] = ss; }
  __syncthreads();
  s = sm[0] + sm[2] + sm[4] + sm[6];
  ss = sm[1] + sm[3] + sm[5] + sm[7];
  const float mean = s * (1.0f / Dmod);
  const float var = ss * (1.0f / Dmod) - mean * mean;
  const float rstd = rsqrtf(var + 1e-6f);
  float4 gg = *(const float4*)(g + t * 4);
  float4 bb = *(const float4*)(b + t * 4);
  bf16x4 o;
  o[0] = (bf16)((v.x - mean) * rstd * gg.x + bb.x);
  o[1] = (bf16)((v.y - mean) * rstd * gg.y + bb.y);
  o[2] = (bf16)((v.z - mean) * rstd * gg.z + bb.z);
  o[3] = (bf16)((v.w - mean) * rstd * gg.w + bb.w);
  *(bf16x4*)(y + t * 4) = o;
}

// -------- f32 -> bf16 bulk convert (for qi) --------
__global__ __launch_bounds__(256) void cvt_f32_bf16(const float* __restrict__ in,
                                                    bf16* __restrict__ out) {
  const size_t i = ((size_t)blockIdx.x * 256 + threadIdx.x) * 4;
  float4 v = *(const float4*)(in + i);
  bf16x4 o;
  o[0] = (bf16)v.x; o[1] = (bf16)v.y; o[2] = (bf16)v.z; o[3] = (bf16)v.w;
  *(bf16x4*)(out + i) = o;
}

// -------- 64x64 tiled transpose, f32 in -> bf16 out ------
__global__ __launch_bounds__(256) void transpose64_f32(
    const float* __restrict__ in, bf16* __restrict__ out, int ld_in,
    int ld_out) {
  __shared__ bf16 tile[64 * 65];
  const int r0 = blockIdx.y * 64, c0 = blockIdx.x * 64;
  const int t = threadIdx.x, cl = t & 63, rq = t >> 6;
#pragma unroll
  for (int it = 0; it < 16; ++it) {
    const int rl = it * 4 + rq;
    tile[cl * 65 + rl] = (bf16)in[(size_t)(r0 + rl) * ld_in + c0 + cl];
  }
  __syncthreads();
#pragma unroll
  for (int it = 0; it < 16; ++it) {
    const int ol = it * 4 + rq;
    out[(size_t)(c0 + ol) * ld_out + r0 + cl] = tile[ol * 65 + cl];
  }
}

// -------- per-(b,m,h) transpose of qih [512,64]->[64,512] for PV Bt ------
__global__ __launch_bounds__(256) void transpose_qih(
    const bf16* __restrict__ qih, bf16* __restrict__ qih_t) {
  __shared__ bf16 tile[64 * 65];
  const int z = blockIdx.z;
  const int bm = z >> 4, h = z & 15;
  const bf16* in = qih + (size_t)bm * Lseq * Dmod + h * DHq;  // 512x64 ld 1024
  bf16* out = qih_t + (size_t)z * DHq * Lseq;                 // 64x512 ld 512
  const int r0 = blockIdx.x * 64;  // lk tile
  const int t = threadIdx.x, cl = t & 63, rq = t >> 6;
#pragma unroll
  for (int it = 0; it < 16; ++it) {
    const int rl = it * 4 + rq;
    tile[cl * 65 + rl] = in[(size_t)(r0 + rl) * Dmod + cl];
  }
  __syncthreads();
#pragma unroll
  for (int it = 0; it < 16; ++it) {
    const int dh = it * 4 + rq;
    out[(size_t)dh * Lseq + r0 + cl] = tile[dh * 65 + cl];
  }
}

extern "C" void kernel_launch(void* const* d_in, const int* in_sizes, int n_in,
                              void* d_out, int out_size, void* d_ws,
                              size_t ws_size, hipStream_t stream) {
  const float* q = (const float*)d_in[0];
  // d_in[1] = k, unused by the reference forward
  const float* qi = (const float*)d_in[2];
  const int* mask = (const int*)d_in[3];
  const float* w_qs = (const float*)d_in[4];
  const float* w_qis = (const float*)d_in[5];
  const float* w_fc = (const float*)d_in[6];
  const float* ln_g = (const float*)d_in[7];
  const float* ln_b = (const float*)d_in[8];

  float* out = (float*)d_out;
  const size_t NE = (size_t)Bq * Mq * Lseq * Dmod;  // 8,388,608
  float* attn = out + NE;  // second tuple element (67,108,864 f32)

  // Scratch parked in the attn output region (dead before fused_attn):
  char* attnc = (char*)attn;  // 268 MB available
  bf16* qib = (bf16*)attnc;                       // 16 MB
  bf16* wqs_t = (bf16*)(attnc + (16u << 20));     // 2 MB
  bf16* wqis_t = (bf16*)(attnc + (18u << 20));    // 2 MB

  char* ws = (char*)d_ws;
  const size_t SZ = NE * sizeof(bf16);  // 16 MiB
  bf16* qn = (bf16*)(ws);               // LN out; reused as out_h later
  bf16* qh = (bf16*)(ws + SZ);
  bf16* qih = (bf16*)(ws + 2 * SZ);
  bf16* qih_t = (bf16*)(ws + 3 * SZ);
  bf16* wfc_t = (bf16*)(ws + 4 * SZ);   // must survive to the last GEMM
  float* denom = (float*)(ws + 4 * SZ + (2u << 20));  // [B,H,L] = 128 KB
  u64* mbits = (u64*)(ws + 4 * SZ + (4u << 20));      // [B,M,L,8] = 512 KB
  bf16* outh = qn;                      // qn dead after first projection

  const int ROWS = Bq * Mq * Lseq;  // 8192

  // 1) input conversions / weight transposes / mask bitmask
  mask_to_bits<<<1024, 256, 0, stream>>>(mask, mbits);
  cvt_f32_bf16<<<NE / 1024, 256, 0, stream>>>(qi, qib);
  transpose64_f32<<<dim3(16, 16), 256, 0, stream>>>(w_qs, wqs_t, Dmod, Dmod);
  transpose64_f32<<<dim3(16, 16), 256, 0, stream>>>(w_qis, wqis_t, Dmod, Dmod);
  transpose64_f32<<<dim3(16, 16), 256, 0, stream>>>(w_fc, wfc_t, Dmod, Dmod);
  hipMemsetAsync(denom, 0, (size_t)Bq * Hq * Lseq * sizeof(float), stream);

  // 2) LayerNorm(q) -> qn
  ln_kernel<<<ROWS, 256, 0, stream>>>(q, ln_g, ln_b, qn);

  // 3) projections with fused per-head L2 normalize
  gemm_bt_128_l2n<<<dim3(Dmod / 128, ROWS / 128), 256, 0, stream>>>(
      qn, wqs_t, qh, Dmod, Dmod, Dmod, Dmod);
  gemm_bt_128_l2n<<<dim3(Dmod / 128, ROWS / 128), 256, 0, stream>>>(
      qib, wqis_t, qih, Dmod, Dmod, Dmod, Dmod);

  // 4) qih^T per (b,m,h) for the PV operand
  transpose_qih<<<dim3(Lseq / 64, 1, Bq * Mq * Hq), 256, 0, stream>>>(qih,
                                                                      qih_t);

  // 5) Pass A: softmax denominators (no P store)
  denom_kernel<<<1024, 256, 0, stream>>>(qh, qih, mbits, denom);

  // 6) Pass B: recompute S, normalize, write attn once, fused PV
  fused_attn<<<1024, 256, 0, stream>>>(qh, qih, qih_t, mbits, denom, attn,
                                       outh);

  // 7) out = out_h @ w_fc + q (f32 out, f32 residual)
  gemm_bt_resid<<<dim3(Dmod / 128, ROWS / 128), 256, 0, stream>>>(
      outh, wfc_t, q, out, Dmod, Dmod, Dmod, Dmod);
}

// Round 6
// 581.942 us; speedup vs baseline: 1.2666x; 1.0320x over previous
//
#include <hip/hip_runtime.h>
#include <hip/hip_bf16.h>
#include <cstdint>
#include <cstddef>

// Problem constants
#define Bq 4
#define Mq 4
#define Lseq 512
#define Dmod 1024
#define Hq 16
#define DHq 64

using bf16 = __bf16;
using bf16x4 = __attribute__((ext_vector_type(4))) __bf16;
using bf16x8 = __attribute__((ext_vector_type(8))) __bf16;
using f32x4 = __attribute__((ext_vector_type(4))) float;
using u64 = unsigned long long;

// -------- async global->LDS, 16B per lane (m97 pattern) --------
__device__ __forceinline__ void gld_lds16(const bf16* g, bf16* l) {
  __builtin_amdgcn_global_load_lds(
      (const __attribute__((address_space(1))) void*)g,
      (__attribute__((address_space(3))) void*)l, 16, 0, 0);
}

// =====================================================================
// GEMM core, double-buffered (T3 minimum 2-phase): C = A * Bt^T.
// Per K-step: vmcnt(0)+barrier -> issue STAGE(t+1) -> ds_read+MFMA(t).
// ONE barrier per step; staging of t+1 retires under MFMA of t.
// LDS: As[2][BM*32], Bs[2][BN*32].
// =====================================================================
template <int WAVES_M, int WAVES_N, int WTM, int WTN>
__device__ __forceinline__ void gemm_core(const bf16* __restrict__ A,
                                          const bf16* __restrict__ Bt,
                                          int K, int lda, int ldb,
                                          bf16* As, bf16* Bs,
                                          f32x4 (&acc)[WTM][WTN]) {
  constexpr int BM = WAVES_M * WTM * 16;
  constexpr int BN = WAVES_N * WTN * 16;
  constexpr int IA = BM / 64;
  constexpr int IB = BN / 64;
  constexpr int ASZ = BM * 32;  // elems per A buffer
  constexpr int BSZ = BN * 32;

  const int t = threadIdx.x;
  const int lane = t & 63;
  const int wave = t >> 6;
  const int wm = wave % WAVES_M;
  const int wn = wave / WAVES_M;
  const int r = t >> 2;            // staging row (0..63)
  const int c8 = (t & 3) * 8;      // staging col (bf16 elems)
  const int fr = lane & 15;        // fragment row/col within 16-tile
  const int fk = (lane >> 4) * 8;  // fragment k offset

  const bf16* Ab = A + (size_t)r * lda + c8;
  const bf16* Bb = Bt + (size_t)r * ldb + c8;

  // prologue: stage k0=0 into buffer 0
#pragma unroll
  for (int i = 0; i < IA; ++i)
    gld_lds16(Ab + (size_t)i * 64 * lda, As + i * 2048 + t * 8);
#pragma unroll
  for (int i = 0; i < IB; ++i)
    gld_lds16(Bb + (size_t)i * 64 * ldb, Bs + i * 2048 + t * 8);

  int cur = 0;
  for (int k0 = 0; k0 < K; k0 += 32) {
    asm volatile("s_waitcnt vmcnt(0)" ::: "memory");
    __syncthreads();  // buf[cur] staged; all reads of buf[cur^1] (t-1) done

    if (k0 + 32 < K) {  // issue next-tile staging into the other buffer
      const int nxt = cur ^ 1;
#pragma unroll
      for (int i = 0; i < IA; ++i)
        gld_lds16(Ab + (size_t)i * 64 * lda + k0 + 32,
                  As + nxt * ASZ + i * 2048 + t * 8);
#pragma unroll
      for (int i = 0; i < IB; ++i)
        gld_lds16(Bb + (size_t)i * 64 * ldb + k0 + 32,
                  Bs + nxt * BSZ + i * 2048 + t * 8);
    }

    const bf16* Ac = As + cur * ASZ;
    const bf16* Bc = Bs + cur * BSZ;
    bf16x8 af[WTM], bfv[WTN];
#pragma unroll
    for (int i = 0; i < WTM; ++i)
      af[i] = *(const bf16x8*)(Ac + (wm * WTM * 16 + i * 16 + fr) * 32 + fk);
#pragma unroll
    for (int j = 0; j < WTN; ++j)
      bfv[j] = *(const bf16x8*)(Bc + (wn * WTN * 16 + j * 16 + fr) * 32 + fk);
    __builtin_amdgcn_s_setprio(1);
#pragma unroll
    for (int i = 0; i < WTM; ++i)
#pragma unroll
      for (int j = 0; j < WTN; ++j)
        acc[i][j] = __builtin_amdgcn_mfma_f32_16x16x32_bf16(af[i], bfv[j],
                                                            acc[i][j], 0, 0, 0);
    __builtin_amdgcn_s_setprio(0);
    cur ^= 1;
  }
}

// -------- projection GEMM with fused per-64-chunk L2 normalize --------
__global__ __launch_bounds__(256) void gemm_bt_128_l2n(
    const bf16* __restrict__ A, const bf16* __restrict__ Bt,
    bf16* __restrict__ C, int K, int lda, int ldb, int ldc) {
  __shared__ __align__(16) bf16 As[2 * 128 * 32];
  __shared__ __align__(16) bf16 Bs[2 * 128 * 32];
  f32x4 acc[4][4] = {};
  const bf16* Ab = A + (size_t)blockIdx.y * 128 * lda;
  const bf16* Bb = Bt + (size_t)blockIdx.x * 128 * ldb;
  gemm_core<2, 2, 4, 4>(Ab, Bb, K, lda, ldb, As, Bs, acc);

  const int t = threadIdx.x, lane = t & 63, wave = t >> 6;
  const int wm = wave & 1, wn = wave >> 1;
  const int cr = (lane >> 4) * 4, cc = lane & 15;
  const size_t row0 = (size_t)blockIdx.y * 128 + wm * 64;
  const size_t col0 = (size_t)blockIdx.x * 128 + wn * 64;
#pragma unroll
  for (int i = 0; i < 4; ++i)
#pragma unroll
    for (int rg = 0; rg < 4; ++rg) {
      float ss = 0.0f;
#pragma unroll
      for (int j = 0; j < 4; ++j) ss += acc[i][j][rg] * acc[i][j][rg];
      ss += __shfl_xor(ss, 1);
      ss += __shfl_xor(ss, 2);
      ss += __shfl_xor(ss, 4);
      ss += __shfl_xor(ss, 8);
      const float r = (ss > 0.0f) ? rsqrtf(ss) : 0.0f;
#pragma unroll
      for (int j = 0; j < 4; ++j)
        C[(row0 + i * 16 + cr + rg) * ldc + col0 + j * 16 + cc] =
            (bf16)(acc[i][j][rg] * r);
    }
}

// -------- final GEMM: C(f32) = A*Bt^T + resid(f32), streaming stores ----
__global__ __launch_bounds__(256) void gemm_bt_resid(
    const bf16* __restrict__ A, const bf16* __restrict__ Bt,
    const float* __restrict__ resid, float* __restrict__ C, int K, int lda,
    int ldb, int ldc) {
  __shared__ __align__(16) bf16 As[2 * 128 * 32];
  __shared__ __align__(16) bf16 Bs[2 * 128 * 32];
  f32x4 acc[4][4] = {};
  const bf16* Ab = A + (size_t)blockIdx.y * 128 * lda;
  const bf16* Bb = Bt + (size_t)blockIdx.x * 128 * ldb;
  gemm_core<2, 2, 4, 4>(Ab, Bb, K, lda, ldb, As, Bs, acc);

  const int t = threadIdx.x, lane = t & 63, wave = t >> 6;
  const int wm = wave & 1, wn = wave >> 1;
  const int cr = (lane >> 4) * 4, cc = lane & 15;
  const size_t row0 = (size_t)blockIdx.y * 128 + wm * 64;
  const size_t col0 = (size_t)blockIdx.x * 128 + wn * 64;
#pragma unroll
  for (int i = 0; i < 4; ++i)
#pragma unroll
    for (int j = 0; j < 4; ++j)
#pragma unroll
      for (int rg = 0; rg < 4; ++rg) {
        size_t idx = (row0 + i * 16 + cr + rg) * ldc + col0 + j * 16 + cc;
        float rv = __builtin_nontemporal_load(resid + idx);
        __builtin_nontemporal_store(acc[i][j][rg] + rv, C + idx);
      }
}

// -------- mask [B,M,L,L] int32 -> bitmask [B,M,L,8] u64 (ballot) --------
__global__ __launch_bounds__(256) void mask_to_bits(
    const int* __restrict__ mask, u64* __restrict__ mb) {
  const int wid = blockIdx.x * 4 + (threadIdx.x >> 6);  // 0..4095
  const int lane = threadIdx.x & 63;
#pragma unroll
  for (int it = 0; it < 16; ++it) {
    const size_t W = (size_t)wid * 16 + it;  // 65536 words total
    const u64 b = __ballot(mask[W * 64 + lane] != 0);
    if (lane == 0) mb[W] = b;
  }
}

// block-index swizzle: each XCD owns 32 consecutive z (2 bm x 16 heads);
// the 4 qtile-siblings of a z dispatch adjacently on the same XCD.
__device__ __forceinline__ void attn_swizzle(int flat, int& z, int& q0) {
  const int slot = flat >> 3;
  z = (flat & 7) * 32 + (slot >> 2);
  q0 = (slot & 3) * 128;
}

// =====================================================================
// Pass A: denom[b,h,q] = sum over (m, lk) of mask * exp(S-1).
// =====================================================================
__global__ __launch_bounds__(256) void denom_kernel(
    const bf16* __restrict__ qh, const bf16* __restrict__ qih,
    const u64* __restrict__ mb, float* __restrict__ denom) {
  __shared__ __align__(16) bf16 Qs[128 * 64];
  __shared__ __align__(16) bf16 Ks[2][64 * 64];

  int z, q0;
  attn_swizzle(blockIdx.x, z, q0);
  const int bm = z >> 4, h = z & 15;

  const int t = threadIdx.x;
  const int lane = t & 63;
  const int wave = t >> 6;
  const int wm = wave & 1, wn = wave >> 1;
  const int fr = lane & 15;
  const int hi = lane >> 4;
  const int sr = t >> 3;   // staging row within round (0..31)
  const int sc = t & 7;    // staging 16B chunk (0..7)

  const bf16* qh_b = qh + ((size_t)bm * Lseq + q0) * Dmod + h * DHq;
  const bf16* qih_b = qih + (size_t)bm * Lseq * Dmod + h * DHq;
  const u64* mrow = mb + (size_t)bm * Lseq * 8;

  // stage Qs (swizzled source cols -> linear LDS; read applies same XOR)
#pragma unroll
  for (int s = 0; s < 4; ++s) {
    const int r = s * 32 + sr;
    gld_lds16(qh_b + (size_t)r * Dmod + ((sc ^ (r & 7)) << 3),
              Qs + s * 2048 + t * 8);
  }
#pragma unroll
  for (int s = 0; s < 2; ++s) {
    const int r = s * 32 + sr;
    gld_lds16(qih_b + (size_t)r * Dmod + ((sc ^ (r & 7)) << 3),
              Ks[0] + s * 2048 + t * 8);
  }

  float racc[4][4] = {};  // per-(i,rg) row partial sums (this lane's cols)

  for (int kt = 0; kt < 8; ++kt) {
    asm volatile("s_waitcnt vmcnt(0)" ::: "memory");
    __syncthreads();

    // prefetch next K tile FIRST (covered by QK^T + epilogue)
    if (kt < 7) {
      const int kv1 = (kt + 1) * 64;
#pragma unroll
      for (int s = 0; s < 2; ++s) {
        const int r = s * 32 + sr;
        gld_lds16(qih_b + (size_t)(kv1 + r) * Dmod + ((sc ^ (r & 7)) << 3),
                  Ks[(kt + 1) & 1] + s * 2048 + t * 8);
      }
    }

    // bitmask words for this kt window (broadcast loads, retire under MFMA)
    u64 mw[4][4];
#pragma unroll
    for (int i = 0; i < 4; ++i)
#pragma unroll
      for (int rg = 0; rg < 4; ++rg)
        mw[i][rg] =
            mrow[(size_t)(q0 + wm * 64 + i * 16 + hi * 4 + rg) * 8 + kt];

    const bf16* Kc = Ks[kt & 1];
    f32x4 acc_s[4][2] = {};
    __builtin_amdgcn_s_setprio(1);
#pragma unroll
    for (int kk = 0; kk < 2; ++kk) {
      bf16x8 bq[4], bk[2];
#pragma unroll
      for (int i = 0; i < 4; ++i) {
        const int row = wm * 64 + i * 16 + fr;
        bq[i] = *(const bf16x8*)(Qs + row * 64 +
                                 ((((kk << 2) + hi) ^ (row & 7)) << 3));
      }
#pragma unroll
      for (int j = 0; j < 2; ++j) {
        const int row = wn * 32 + j * 16 + fr;
        bk[j] = *(const bf16x8*)(Kc + row * 64 +
                                 ((((kk << 2) + hi) ^ (row & 7)) << 3));
      }
#pragma unroll
      for (int i = 0; i < 4; ++i)
#pragma unroll
        for (int j = 0; j < 2; ++j)
          acc_s[i][j] = __builtin_amdgcn_mfma_f32_16x16x32_bf16(
              bq[i], bk[j], acc_s[i][j], 0, 0, 0);
    }
    __builtin_amdgcn_s_setprio(0);

#pragma unroll
    for (int i = 0; i < 4; ++i)
#pragma unroll
      for (int rg = 0; rg < 4; ++rg) {
        const unsigned hw = (unsigned)(mw[i][rg] >> (wn * 32));
#pragma unroll
        for (int j = 0; j < 2; ++j)
          if ((hw >> (j * 16 + fr)) & 1)
            racc[i][rg] += __expf(acc_s[i][j][rg] - 1.0f);
      }
  }

  // reduce across the 16 column-lanes and atomically add per row
  float* dp = denom + ((size_t)(bm >> 2) * Hq + h) * Lseq + q0 + wm * 64;
#pragma unroll
  for (int i = 0; i < 4; ++i)
#pragma unroll
    for (int rg = 0; rg < 4; ++rg) {
      float rs = racc[i][rg];
      rs += __shfl_xor(rs, 1);
      rs += __shfl_xor(rs, 2);
      rs += __shfl_xor(rs, 4);
      rs += __shfl_xor(rs, 8);
      if (fr == 0) atomicAdd(dp + i * 16 + hi * 4 + rg, rs);
    }
}

// =====================================================================
// Pass B: recompute S, normalize with 1/denom, write attn f32 once (NT),
// bounce P through swizzled LDS, fused PV. Fully double-buffered.
// =====================================================================
__global__ __launch_bounds__(256) void fused_attn(
    const bf16* __restrict__ qh, const bf16* __restrict__ qih,
    const bf16* __restrict__ qih_t, const u64* __restrict__ mb,
    const float* __restrict__ denom, float* __restrict__ attn,
    bf16* __restrict__ outh) {
  __shared__ __align__(16) bf16 Qs[128 * 64];
  __shared__ __align__(16) bf16 Ks[2][64 * 64];
  __shared__ __align__(16) bf16 Vs[2][64 * 64];
  __shared__ __align__(16) bf16 Ps[2][128 * 64];

  int z, q0;
  attn_swizzle(blockIdx.x, z, q0);
  const int bm = z >> 4, h = z & 15;

  const int t = threadIdx.x;
  const int lane = t & 63;
  const int wave = t >> 6;
  const int wm = wave & 1, wn = wave >> 1;
  const int fr = lane & 15;
  const int hi = lane >> 4;
  const int sr = t >> 3;
  const int sc = t & 7;

  const bf16* qh_b = qh + ((size_t)bm * Lseq + q0) * Dmod + h * DHq;
  const bf16* qih_b = qih + (size_t)bm * Lseq * Dmod + h * DHq;
  const bf16* vt_b = qih_t + (size_t)z * DHq * Lseq;
  const u64* mrow = mb + (size_t)bm * Lseq * 8;
  float* arow = attn + (size_t)z * Lseq * Lseq;

  // stage Qs (resident for whole kernel)
#pragma unroll
  for (int s = 0; s < 4; ++s) {
    const int r = s * 32 + sr;
    gld_lds16(qh_b + (size_t)r * Dmod + ((sc ^ (r & 7)) << 3),
              Qs + s * 2048 + t * 8);
  }
  // prologue staging of K(0), V(0)
#pragma unroll
  for (int s = 0; s < 2; ++s) {
    const int r = s * 32 + sr;
    gld_lds16(qih_b + (size_t)r * Dmod + ((sc ^ (r & 7)) << 3),
              Ks[0] + s * 2048 + t * 8);
    gld_lds16(vt_b + (size_t)r * Lseq + ((sc ^ (r & 7)) << 3),
              Vs[0] + s * 2048 + t * 8);
  }

  // 1/denom for this lane's 16 rows
  const float* drow = denom + ((size_t)(bm >> 2) * Hq + h) * Lseq + q0;
  float invd[4][4];
#pragma unroll
  for (int i = 0; i < 4; ++i)
#pragma unroll
    for (int rg = 0; rg < 4; ++rg) {
      const float d = drow[wm * 64 + i * 16 + hi * 4 + rg];
      invd[i][rg] = (d > 0.0f) ? 1.0f / d : 0.0f;
    }

  f32x4 acc_o[4][2] = {};

  for (int kt = 0; kt < 8; ++kt) {
    const int kv0 = kt * 64;
    asm volatile("s_waitcnt vmcnt(0)" ::: "memory");
    __syncthreads();  // (1) K/V(kt) landed; Ps[kt&1] free (PV kt-2 done)

    // prefetch K/V(kt+1) into the other buffers (spans QK^T+epi+PV)
    if (kt < 7) {
      const int kv1 = kv0 + 64;
#pragma unroll
      for (int s = 0; s < 2; ++s) {
        const int r = s * 32 + sr;
        gld_lds16(qih_b + (size_t)(kv1 + r) * Dmod + ((sc ^ (r & 7)) << 3),
                  Ks[(kt + 1) & 1] + s * 2048 + t * 8);
        gld_lds16(vt_b + (size_t)r * Lseq + kv1 + ((sc ^ (r & 7)) << 3),
                  Vs[(kt + 1) & 1] + s * 2048 + t * 8);
      }
    }

    // bitmask words for this kt window (retire under MFMA)
    u64 mw[4][4];
#pragma unroll
    for (int i = 0; i < 4; ++i)
#pragma unroll
      for (int rg = 0; rg < 4; ++rg)
        mw[i][rg] =
            mrow[(size_t)(q0 + wm * 64 + i * 16 + hi * 4 + rg) * 8 + kt];

    // ---- QK^T: S[128,64], wave tile 64 x 32 ----
    const bf16* Kc = Ks[kt & 1];
    f32x4 acc_s[4][2] = {};
    __builtin_amdgcn_s_setprio(1);
#pragma unroll
    for (int kk = 0; kk < 2; ++kk) {
      bf16x8 bq[4], bk[2];
#pragma unroll
      for (int i = 0; i < 4; ++i) {
        const int row = wm * 64 + i * 16 + fr;
        bq[i] = *(const bf16x8*)(Qs + row * 64 +
                                 ((((kk << 2) + hi) ^ (row & 7)) << 3));
      }
#pragma unroll
      for (int j = 0; j < 2; ++j) {
        const int row = wn * 32 + j * 16 + fr;
        bk[j] = *(const bf16x8*)(Kc + row * 64 +
                                 ((((kk << 2) + hi) ^ (row & 7)) << 3));
      }
#pragma unroll
      for (int i = 0; i < 4; ++i)
#pragma unroll
        for (int j = 0; j < 2; ++j)
          acc_s[i][j] = __builtin_amdgcn_mfma_f32_16x16x32_bf16(
              bq[i], bk[j], acc_s[i][j], 0, 0, 0);
    }
    __builtin_amdgcn_s_setprio(0);

    // ---- epilogue: mask-bit, exp, normalize, write attn (NT), write Ps --
    bf16* Pc = Ps[kt & 1];
#pragma unroll
    for (int i = 0; i < 4; ++i)
#pragma unroll
      for (int j = 0; j < 2; ++j)
#pragma unroll
        for (int rg = 0; rg < 4; ++rg) {
          const int ql = wm * 64 + i * 16 + hi * 4 + rg;
          const int cl = wn * 32 + j * 16 + fr;
          const unsigned hw = (unsigned)(mw[i][rg] >> (wn * 32));
          float p = 0.0f;
          if ((hw >> (j * 16 + fr)) & 1)
            p = __expf(acc_s[i][j][rg] - 1.0f) * invd[i][rg];
          __builtin_nontemporal_store(
              p, arow + (size_t)(q0 + ql) * Lseq + kv0 + cl);
          Pc[ql * 64 + (((cl >> 3) ^ (ql & 7)) << 3) + (cl & 7)] = (bf16)p;
        }
    asm volatile("s_waitcnt lgkmcnt(0)" ::: "memory");
    __builtin_amdgcn_s_barrier();  // (2) raw: staging/NT stores stay in flight

    // ---- PV: acc_o += P[128,64] * V^T (Vs = qih_t tile [dh][lk]) ----
    const bf16* Vc = Vs[kt & 1];
    __builtin_amdgcn_s_setprio(1);
#pragma unroll
    for (int kk = 0; kk < 2; ++kk) {
      bf16x8 ap[4], bv[2];
#pragma unroll
      for (int i = 0; i < 4; ++i) {
        const int row = wm * 64 + i * 16 + fr;
        ap[i] = *(const bf16x8*)(Pc + row * 64 +
                                 ((((kk << 2) + hi) ^ (row & 7)) << 3));
      }
#pragma unroll
      for (int j = 0; j < 2; ++j) {
        const int row = wn * 32 + j * 16 + fr;
        bv[j] = *(const bf16x8*)(Vc + row * 64 +
                                 ((((kk << 2) + hi) ^ (row & 7)) << 3));
      }
#pragma unroll
      for (int i = 0; i < 4; ++i)
#pragma unroll
        for (int j = 0; j < 2; ++j)
          acc_o[i][j] = __builtin_amdgcn_mfma_f32_16x16x32_bf16(
              ap[i], bv[j], acc_o[i][j], 0, 0, 0);
    }
    __builtin_amdgcn_s_setprio(0);
  }

  // write outh tile [128 x 64] (head h's column span)
  bf16* Cb = outh + ((size_t)bm * Lseq + q0) * Dmod + h * DHq;
#pragma unroll
  for (int i = 0; i < 4; ++i)
#pragma unroll
    for (int j = 0; j < 2; ++j)
#pragma unroll
      for (int rg = 0; rg < 4; ++rg)
        Cb[(size_t)(wm * 64 + i * 16 + hi * 4 + rg) * Dmod + wn * 32 +
           j * 16 + fr] = (bf16)acc_o[i][j][rg];
}

// -------- LayerNorm over D=1024, f32 in -> bf16 out, one block/row -------
__global__ __launch_bounds__(256) void ln_kernel(const float* __restrict__ q,
                                                 const float* __restrict__ g,
                                                 const float* __restrict__ b,
                                                 bf16* __restrict__ qn) {
  const size_t row = blockIdx.x;
  const float* x = q + row * Dmod;
  bf16* y = qn + row * Dmod;
  const int t = threadIdx.x;
  float4 v = *(const float4*)(x + t * 4);
  float s = v.x + v.y + v.z + v.w;
  float ss = v.x * v.x + v.y * v.y + v.z * v.z + v.w * v.w;
  for (int off = 32; off; off >>= 1) {
    s += __shfl_xor(s, off);
    ss += __shfl_xor(ss, off);
  }
  __shared__ float sm[8];
  const int wave = t >> 6, lane = t & 63;
  if (lane == 0) { sm[wave * 2] = s; sm[wave * 2 + 1] = ss; }
  __syncthreads();
  s = sm[0] + sm[2] + sm[4] + sm[6];
  ss = sm[1] + sm[3] + sm[5] + sm[7];
  const float mean = s * (1.0f / Dmod);
  const float var = ss * (1.0f / Dmod) - mean * mean;
  const float rstd = rsqrtf(var + 1e-6f);
  float4 gg = *(const float4*)(g + t * 4);
  float4 bb = *(const float4*)(b + t * 4);
  bf16x4 o;
  o[0] = (bf16)((v.x - mean) * rstd * gg.x + bb.x);
  o[1] = (bf16)((v.y - mean) * rstd * gg.y + bb.y);
  o[2] = (bf16)((v.z - mean) * rstd * gg.z + bb.z);
  o[3] = (bf16)((v.w - mean) * rstd * gg.w + bb.w);
  *(bf16x4*)(y + t * 4) = o;
}

// -------- f32 -> bf16 bulk convert (for qi) --------
__global__ __launch_bounds__(256) void cvt_f32_bf16(const float* __restrict__ in,
                                                    bf16* __restrict__ out) {
  const size_t i = ((size_t)blockIdx.x * 256 + threadIdx.x) * 4;
  float4 v = *(const float4*)(in + i);
  bf16x4 o;
  o[0] = (bf16)v.x; o[1] = (bf16)v.y; o[2] = (bf16)v.z; o[3] = (bf16)v.w;
  *(bf16x4*)(out + i) = o;
}

// -------- 64x64 tiled transpose, f32 in -> bf16 out ------
__global__ __launch_bounds__(256) void transpose64_f32(
    const float* __restrict__ in, bf16* __restrict__ out, int ld_in,
    int ld_out) {
  __shared__ bf16 tile[64 * 65];
  const int r0 = blockIdx.y * 64, c0 = blockIdx.x * 64;
  const int t = threadIdx.x, cl = t & 63, rq = t >> 6;
#pragma unroll
  for (int it = 0; it < 16; ++it) {
    const int rl = it * 4 + rq;
    tile[cl * 65 + rl] = (bf16)in[(size_t)(r0 + rl) * ld_in + c0 + cl];
  }
  __syncthreads();
#pragma unroll
  for (int it = 0; it < 16; ++it) {
    const int ol = it * 4 + rq;
    out[(size_t)(c0 + ol) * ld_out + r0 + cl] = tile[ol * 65 + cl];
  }
}

// -------- per-(b,m,h) transpose of qih [512,64]->[64,512] for PV Bt ------
__global__ __launch_bounds__(256) void transpose_qih(
    const bf16* __restrict__ qih, bf16* __restrict__ qih_t) {
  __shared__ bf16 tile[64 * 65];
  const int z = blockIdx.z;
  const int bm = z >> 4, h = z & 15;
  const bf16* in = qih + (size_t)bm * Lseq * Dmod + h * DHq;  // 512x64 ld 1024
  bf16* out = qih_t + (size_t)z * DHq * Lseq;                 // 64x512 ld 512
  const int r0 = blockIdx.x * 64;  // lk tile
  const int t = threadIdx.x, cl = t & 63, rq = t >> 6;
#pragma unroll
  for (int it = 0; it < 16; ++it) {
    const int rl = it * 4 + rq;
    tile[cl * 65 + rl] = in[(size_t)(r0 + rl) * Dmod + cl];
  }
  __syncthreads();
#pragma unroll
  for (int it = 0; it < 16; ++it) {
    const int dh = it * 4 + rq;
    out[(size_t)dh * Lseq + r0 + cl] = tile[dh * 65 + cl];
  }
}

extern "C" void kernel_launch(void* const* d_in, const int* in_sizes, int n_in,
                              void* d_out, int out_size, void* d_ws,
                              size_t ws_size, hipStream_t stream) {
  const float* q = (const float*)d_in[0];
  // d_in[1] = k, unused by the reference forward
  const float* qi = (const float*)d_in[2];
  const int* mask = (const int*)d_in[3];
  const float* w_qs = (const float*)d_in[4];
  const float* w_qis = (const float*)d_in[5];
  const float* w_fc = (const float*)d_in[6];
  const float* ln_g = (const float*)d_in[7];
  const float* ln_b = (const float*)d_in[8];

  float* out = (float*)d_out;
  const size_t NE = (size_t)Bq * Mq * Lseq * Dmod;  // 8,388,608
  float* attn = out + NE;  // second tuple element (67,108,864 f32)

  // Scratch parked in the attn output region (dead before fused_attn):
  char* attnc = (char*)attn;  // 268 MB available
  bf16* qib = (bf16*)attnc;                       // 16 MB
  bf16* wqs_t = (bf16*)(attnc + (16u << 20));     // 2 MB
  bf16* wqis_t = (bf16*)(attnc + (18u << 20));    // 2 MB

  char* ws = (char*)d_ws;
  const size_t SZ = NE * sizeof(bf16);  // 16 MiB
  bf16* qn = (bf16*)(ws);               // LN out; reused as out_h later
  bf16* qh = (bf16*)(ws + SZ);
  bf16* qih = (bf16*)(ws + 2 * SZ);
  bf16* qih_t = (bf16*)(ws + 3 * SZ);
  bf16* wfc_t = (bf16*)(ws + 4 * SZ);   // must survive to the last GEMM
  float* denom = (float*)(ws + 4 * SZ + (2u << 20));  // [B,H,L] = 128 KB
  u64* mbits = (u64*)(ws + 4 * SZ + (4u << 20));      // [B,M,L,8] = 512 KB
  bf16* outh = qn;                      // qn dead after first projection

  const int ROWS = Bq * Mq * Lseq;  // 8192

  // 1) input conversions / weight transposes / mask bitmask
  mask_to_bits<<<1024, 256, 0, stream>>>(mask, mbits);
  cvt_f32_bf16<<<NE / 1024, 256, 0, stream>>>(qi, qib);
  transpose64_f32<<<dim3(16, 16), 256, 0, stream>>>(w_qs, wqs_t, Dmod, Dmod);
  transpose64_f32<<<dim3(16, 16), 256, 0, stream>>>(w_qis, wqis_t, Dmod, Dmod);
  transpose64_f32<<<dim3(16, 16), 256, 0, stream>>>(w_fc, wfc_t, Dmod, Dmod);
  hipMemsetAsync(denom, 0, (size_t)Bq * Hq * Lseq * sizeof(float), stream);

  // 2) LayerNorm(q) -> qn
  ln_kernel<<<ROWS, 256, 0, stream>>>(q, ln_g, ln_b, qn);

  // 3) projections with fused per-head L2 normalize
  gemm_bt_128_l2n<<<dim3(Dmod / 128, ROWS / 128), 256, 0, stream>>>(
      qn, wqs_t, qh, Dmod, Dmod, Dmod, Dmod);
  gemm_bt_128_l2n<<<dim3(Dmod / 128, ROWS / 128), 256, 0, stream>>>(
      qib, wqis_t, qih, Dmod, Dmod, Dmod, Dmod);

  // 4) qih^T per (b,m,h) for the PV operand
  transpose_qih<<<dim3(Lseq / 64, 1, Bq * Mq * Hq), 256, 0, stream>>>(qih,
                                                                      qih_t);

  // 5) Pass A: softmax denominators (no P store)
  denom_kernel<<<1024, 256, 0, stream>>>(qh, qih, mbits, denom);

  // 6) Pass B: recompute S, normalize, write attn once, fused PV
  fused_attn<<<1024, 256, 0, stream>>>(qh, qih, qih_t, mbits, denom, attn,
                                       outh);

  // 7) out = out_h @ w_fc + q (f32 out, f32 residual)
  gemm_bt_resid<<<dim3(Dmod / 128, ROWS / 128), 256, 0, stream>>>(
      outh, wfc_t, q, out, Dmod, Dmod, Dmod, Dmod);
}

// Round 7
// 564.049 us; speedup vs baseline: 1.3068x; 1.0317x over previous
//
#include <hip/hip_runtime.h>
#include <hip/hip_bf16.h>
#include <cstdint>
#include <cstddef>

// Problem constants
#define Bq 4
#define Mq 4
#define Lseq 512
#define Dmod 1024
#define Hq 16
#define DHq 64

using bf16 = __bf16;
using bf16x4 = __attribute__((ext_vector_type(4))) __bf16;
using bf16x8 = __attribute__((ext_vector_type(8))) __bf16;
using f32x4 = __attribute__((ext_vector_type(4))) float;
using u64 = unsigned long long;

// -------- async global->LDS, 16B per lane (m97 pattern) --------
__device__ __forceinline__ void gld_lds16(const bf16* g, bf16* l) {
  __builtin_amdgcn_global_load_lds(
      (const __attribute__((address_space(1))) void*)g,
      (__attribute__((address_space(3))) void*)l, 16, 0, 0);
}

// =====================================================================
// GEMM core, double-buffered (T3 minimum 2-phase): C = A * Bt^T.
// =====================================================================
template <int WAVES_M, int WAVES_N, int WTM, int WTN>
__device__ __forceinline__ void gemm_core(const bf16* __restrict__ A,
                                          const bf16* __restrict__ Bt,
                                          int K, int lda, int ldb,
                                          bf16* As, bf16* Bs,
                                          f32x4 (&acc)[WTM][WTN]) {
  constexpr int BM = WAVES_M * WTM * 16;
  constexpr int BN = WAVES_N * WTN * 16;
  constexpr int IA = BM / 64;
  constexpr int IB = BN / 64;
  constexpr int ASZ = BM * 32;
  constexpr int BSZ = BN * 32;

  const int t = threadIdx.x;
  const int lane = t & 63;
  const int wave = t >> 6;
  const int wm = wave % WAVES_M;
  const int wn = wave / WAVES_M;
  const int r = t >> 2;
  const int c8 = (t & 3) * 8;
  const int fr = lane & 15;
  const int fk = (lane >> 4) * 8;

  const bf16* Ab = A + (size_t)r * lda + c8;
  const bf16* Bb = Bt + (size_t)r * ldb + c8;

#pragma unroll
  for (int i = 0; i < IA; ++i)
    gld_lds16(Ab + (size_t)i * 64 * lda, As + i * 2048 + t * 8);
#pragma unroll
  for (int i = 0; i < IB; ++i)
    gld_lds16(Bb + (size_t)i * 64 * ldb, Bs + i * 2048 + t * 8);

  int cur = 0;
  for (int k0 = 0; k0 < K; k0 += 32) {
    asm volatile("s_waitcnt vmcnt(0)" ::: "memory");
    __syncthreads();

    if (k0 + 32 < K) {
      const int nxt = cur ^ 1;
#pragma unroll
      for (int i = 0; i < IA; ++i)
        gld_lds16(Ab + (size_t)i * 64 * lda + k0 + 32,
                  As + nxt * ASZ + i * 2048 + t * 8);
#pragma unroll
      for (int i = 0; i < IB; ++i)
        gld_lds16(Bb + (size_t)i * 64 * ldb + k0 + 32,
                  Bs + nxt * BSZ + i * 2048 + t * 8);
    }

    const bf16* Ac = As + cur * ASZ;
    const bf16* Bc = Bs + cur * BSZ;
    bf16x8 af[WTM], bfv[WTN];
#pragma unroll
    for (int i = 0; i < WTM; ++i)
      af[i] = *(const bf16x8*)(Ac + (wm * WTM * 16 + i * 16 + fr) * 32 + fk);
#pragma unroll
    for (int j = 0; j < WTN; ++j)
      bfv[j] = *(const bf16x8*)(Bc + (wn * WTN * 16 + j * 16 + fr) * 32 + fk);
    __builtin_amdgcn_s_setprio(1);
#pragma unroll
    for (int i = 0; i < WTM; ++i)
#pragma unroll
      for (int j = 0; j < WTN; ++j)
        acc[i][j] = __builtin_amdgcn_mfma_f32_16x16x32_bf16(af[i], bfv[j],
                                                            acc[i][j], 0, 0, 0);
    __builtin_amdgcn_s_setprio(0);
    cur ^= 1;
  }
}

// =====================================================================
// Merged projection GEMM (blockIdx.z picks operands) with fused per-head
// L2 normalize. z=1 additionally emits the transposed qih_t tile via a
// padded LDS bounce (replaces the transpose_qih kernel).
// LDS: As 16K + Bs 16K + Ts 17.5K = 49.5 KB -> 3 blocks/CU.
// =====================================================================
__global__ __launch_bounds__(256) void gemm_proj(
    const bf16* __restrict__ A0, const bf16* __restrict__ B0,
    bf16* __restrict__ C0, const bf16* __restrict__ A1,
    const bf16* __restrict__ B1, bf16* __restrict__ C1,
    bf16* __restrict__ qih_t) {
  __shared__ __align__(16) bf16 As[2 * 128 * 32];
  __shared__ __align__(16) bf16 Bs[2 * 128 * 32];
  __shared__ __align__(16) bf16 Ts[64 * 140];  // [dh][row] padded

  const int zz = blockIdx.z;
  const bf16* A = zz ? A1 : A0;
  const bf16* Bt = zz ? B1 : B0;
  bf16* C = zz ? C1 : C0;

  f32x4 acc[4][4] = {};
  gemm_core<2, 2, 4, 4>(A + (size_t)blockIdx.y * 128 * Dmod,
                        Bt + (size_t)blockIdx.x * 128 * Dmod, Dmod, Dmod,
                        Dmod, As, Bs, acc);

  const int t = threadIdx.x, lane = t & 63, wave = t >> 6;
  const int wm = wave & 1, wn = wave >> 1;
  const int cr = (lane >> 4) * 4, cc = lane & 15;
  const size_t row0 = (size_t)blockIdx.y * 128 + wm * 64;
  const size_t col0 = (size_t)blockIdx.x * 128 + wn * 64;

  float rinv[4][4];
#pragma unroll
  for (int i = 0; i < 4; ++i)
#pragma unroll
    for (int rg = 0; rg < 4; ++rg) {
      float ss = 0.0f;
#pragma unroll
      for (int j = 0; j < 4; ++j) ss += acc[i][j][rg] * acc[i][j][rg];
      ss += __shfl_xor(ss, 1);
      ss += __shfl_xor(ss, 2);
      ss += __shfl_xor(ss, 4);
      ss += __shfl_xor(ss, 8);
      rinv[i][rg] = (ss > 0.0f) ? rsqrtf(ss) : 0.0f;
#pragma unroll
      for (int j = 0; j < 4; ++j)
        C[(row0 + i * 16 + cr + rg) * Dmod + col0 + j * 16 + cc] =
            (bf16)(acc[i][j][rg] * rinv[i][rg]);
    }

  if (zz) {
    // emit qih_t[(bm*16+h)][dh][lq] for the block's two heads
    const int bm = (int)(blockIdx.y >> 2);
    const int lq0 = ((int)blockIdx.y & 3) * 128;
#pragma unroll
    for (int hh = 0; hh < 2; ++hh) {
      __syncthreads();  // Ts free
      if (wn == hh) {
#pragma unroll
        for (int i = 0; i < 4; ++i)
#pragma unroll
          for (int j = 0; j < 4; ++j)
#pragma unroll
            for (int rg = 0; rg < 4; ++rg)
              Ts[(j * 16 + cc) * 140 + wm * 64 + i * 16 + cr + rg] =
                  (bf16)(acc[i][j][rg] * rinv[i][rg]);
      }
      __syncthreads();  // Ts full
      const int h = 2 * (int)blockIdx.x + hh;
      bf16* op = qih_t + ((size_t)(bm * Hq + h) * DHq) * Lseq;
      const int dh = t >> 2, c0 = (t & 3) * 32;
#pragma unroll
      for (int v = 0; v < 4; ++v)
        *(bf16x8*)(op + (size_t)dh * Lseq + lq0 + c0 + v * 8) =
            *(const bf16x8*)(Ts + dh * 140 + c0 + v * 8);
    }
  }
}

// -------- final GEMM: C(f32) = A*Bt^T + resid(f32), streaming stores ----
__global__ __launch_bounds__(256) void gemm_bt_resid(
    const bf16* __restrict__ A, const bf16* __restrict__ Bt,
    const float* __restrict__ resid, float* __restrict__ C, int K, int lda,
    int ldb, int ldc) {
  __shared__ __align__(16) bf16 As[2 * 128 * 32];
  __shared__ __align__(16) bf16 Bs[2 * 128 * 32];
  f32x4 acc[4][4] = {};
  const bf16* Ab = A + (size_t)blockIdx.y * 128 * lda;
  const bf16* Bb = Bt + (size_t)blockIdx.x * 128 * ldb;
  gemm_core<2, 2, 4, 4>(Ab, Bb, K, lda, ldb, As, Bs, acc);

  const int t = threadIdx.x, lane = t & 63, wave = t >> 6;
  const int wm = wave & 1, wn = wave >> 1;
  const int cr = (lane >> 4) * 4, cc = lane & 15;
  const size_t row0 = (size_t)blockIdx.y * 128 + wm * 64;
  const size_t col0 = (size_t)blockIdx.x * 128 + wn * 64;
#pragma unroll
  for (int i = 0; i < 4; ++i)
#pragma unroll
    for (int j = 0; j < 4; ++j)
#pragma unroll
      for (int rg = 0; rg < 4; ++rg) {
        size_t idx = (row0 + i * 16 + cr + rg) * ldc + col0 + j * 16 + cc;
        float rv = __builtin_nontemporal_load(resid + idx);
        __builtin_nontemporal_store(acc[i][j][rg] + rv, C + idx);
      }
}

// =====================================================================
// Prep mega-kernel: block-range role dispatch.
//   [0, 8192)        LayerNorm rows
//   [8192, 9216)     mask -> bitmask
//   [9216, 9984)     3x weight transpose (256 blocks each)
//   [9984, 12032)    qi f32->bf16 (grid-stride over 8192 virtual blocks)
// =====================================================================
__global__ __launch_bounds__(256) void prep_kernel(
    const float* __restrict__ q, const float* __restrict__ g,
    const float* __restrict__ bb_, bf16* __restrict__ qn,
    const int* __restrict__ mask, u64* __restrict__ mb,
    const float* __restrict__ w_qs, bf16* __restrict__ wqs_t,
    const float* __restrict__ w_qis, bf16* __restrict__ wqis_t,
    const float* __restrict__ w_fc, bf16* __restrict__ wfc_t,
    const float* __restrict__ qi, bf16* __restrict__ qib) {
  __shared__ float sm[8];
  __shared__ bf16 tile[64 * 65];
  const int b = blockIdx.x;
  const int t = threadIdx.x;

  if (b < 8192) {  // ---- LayerNorm ----
    const size_t row = b;
    const float* x = q + row * Dmod;
    bf16* y = qn + row * Dmod;
    float4 v = *(const float4*)(x + t * 4);
    float s = v.x + v.y + v.z + v.w;
    float ss = v.x * v.x + v.y * v.y + v.z * v.z + v.w * v.w;
    for (int off = 32; off; off >>= 1) {
      s += __shfl_xor(s, off);
      ss += __shfl_xor(ss, off);
    }
    const int wave = t >> 6, lane = t & 63;
    if (lane == 0) { sm[wave * 2] = s; sm[wave * 2 + 1] = ss; }
    __syncthreads();
    s = sm[0] + sm[2] + sm[4] + sm[6];
    ss = sm[1] + sm[3] + sm[5] + sm[7];
    const float mean = s * (1.0f / Dmod);
    const float var = ss * (1.0f / Dmod) - mean * mean;
    const float rstd = rsqrtf(var + 1e-6f);
    float4 gg = *(const float4*)(g + t * 4);
    float4 bv = *(const float4*)(bb_ + t * 4);
    bf16x4 o;
    o[0] = (bf16)((v.x - mean) * rstd * gg.x + bv.x);
    o[1] = (bf16)((v.y - mean) * rstd * gg.y + bv.y);
    o[2] = (bf16)((v.z - mean) * rstd * gg.z + bv.z);
    o[3] = (bf16)((v.w - mean) * rstd * gg.w + bv.w);
    *(bf16x4*)(y + t * 4) = o;
  } else if (b < 9216) {  // ---- mask -> bitmask ----
    const int wid = (b - 8192) * 4 + (t >> 6);
    const int lane = t & 63;
#pragma unroll
    for (int it = 0; it < 16; ++it) {
      const size_t W = (size_t)wid * 16 + it;
      const u64 bits = __ballot(mask[W * 64 + lane] != 0);
      if (lane == 0) mb[W] = bits;
    }
  } else if (b < 9984) {  // ---- weight transposes ----
    const int which = (b - 9216) >> 8;
    const int it = (b - 9216) & 255;
    const float* in = which == 0 ? w_qs : (which == 1 ? w_qis : w_fc);
    bf16* outp = which == 0 ? wqs_t : (which == 1 ? wqis_t : wfc_t);
    const int r0 = (it >> 4) * 64, c0 = (it & 15) * 64;
    const int cl = t & 63, rq = t >> 6;
#pragma unroll
    for (int k = 0; k < 16; ++k) {
      const int rl = k * 4 + rq;
      tile[cl * 65 + rl] = (bf16)in[(size_t)(r0 + rl) * Dmod + c0 + cl];
    }
    __syncthreads();
#pragma unroll
    for (int k = 0; k < 16; ++k) {
      const int ol = k * 4 + rq;
      outp[(size_t)(c0 + ol) * Dmod + r0 + cl] = tile[ol * 65 + cl];
    }
  } else {  // ---- qi f32 -> bf16 (grid-stride) ----
    for (int vb = b - 9984; vb < 8192; vb += 2048) {
      const size_t i = ((size_t)vb * 256 + t) * 4;
      float4 v = *(const float4*)(qi + i);
      bf16x4 o;
      o[0] = (bf16)v.x; o[1] = (bf16)v.y;
      o[2] = (bf16)v.z; o[3] = (bf16)v.w;
      *(bf16x4*)(qib + i) = o;
    }
  }
}

// block-index swizzle: each XCD owns 32 consecutive z (2 bm x 16 heads)
__device__ __forceinline__ void attn_swizzle(int flat, int& z, int& q0) {
  const int slot = flat >> 3;
  z = (flat & 7) * 32 + (slot >> 2);
  q0 = (slot & 3) * 128;
}

// =====================================================================
// Pass A: denom[b,h,q] = sum over (m, lk) of mask * exp(S-1).
// =====================================================================
__global__ __launch_bounds__(256) void denom_kernel(
    const bf16* __restrict__ qh, const bf16* __restrict__ qih,
    const u64* __restrict__ mb, float* __restrict__ denom) {
  __shared__ __align__(16) bf16 Qs[128 * 64];
  __shared__ __align__(16) bf16 Ks[2][64 * 64];

  int z, q0;
  attn_swizzle(blockIdx.x, z, q0);
  const int bm = z >> 4, h = z & 15;

  const int t = threadIdx.x;
  const int lane = t & 63;
  const int wave = t >> 6;
  const int wm = wave & 1, wn = wave >> 1;
  const int fr = lane & 15;
  const int hi = lane >> 4;
  const int sr = t >> 3;
  const int sc = t & 7;

  const bf16* qh_b = qh + ((size_t)bm * Lseq + q0) * Dmod + h * DHq;
  const bf16* qih_b = qih + (size_t)bm * Lseq * Dmod + h * DHq;
  const u64* mrow = mb + (size_t)bm * Lseq * 8;

#pragma unroll
  for (int s = 0; s < 4; ++s) {
    const int r = s * 32 + sr;
    gld_lds16(qh_b + (size_t)r * Dmod + ((sc ^ (r & 7)) << 3),
              Qs + s * 2048 + t * 8);
  }
#pragma unroll
  for (int s = 0; s < 2; ++s) {
    const int r = s * 32 + sr;
    gld_lds16(qih_b + (size_t)r * Dmod + ((sc ^ (r & 7)) << 3),
              Ks[0] + s * 2048 + t * 8);
  }

  float racc[4][4] = {};

  for (int kt = 0; kt < 8; ++kt) {
    asm volatile("s_waitcnt vmcnt(0)" ::: "memory");
    __syncthreads();

    if (kt < 7) {
      const int kv1 = (kt + 1) * 64;
#pragma unroll
      for (int s = 0; s < 2; ++s) {
        const int r = s * 32 + sr;
        gld_lds16(qih_b + (size_t)(kv1 + r) * Dmod + ((sc ^ (r & 7)) << 3),
                  Ks[(kt + 1) & 1] + s * 2048 + t * 8);
      }
    }

    u64 mw[4][4];
#pragma unroll
    for (int i = 0; i < 4; ++i)
#pragma unroll
      for (int rg = 0; rg < 4; ++rg)
        mw[i][rg] =
            mrow[(size_t)(q0 + wm * 64 + i * 16 + hi * 4 + rg) * 8 + kt];

    const bf16* Kc = Ks[kt & 1];
    f32x4 acc_s[4][2] = {};
    __builtin_amdgcn_s_setprio(1);
#pragma unroll
    for (int kk = 0; kk < 2; ++kk) {
      bf16x8 bq[4], bk[2];
#pragma unroll
      for (int i = 0; i < 4; ++i) {
        const int row = wm * 64 + i * 16 + fr;
        bq[i] = *(const bf16x8*)(Qs + row * 64 +
                                 ((((kk << 2) + hi) ^ (row & 7)) << 3));
      }
#pragma unroll
      for (int j = 0; j < 2; ++j) {
        const int row = wn * 32 + j * 16 + fr;
        bk[j] = *(const bf16x8*)(Kc + row * 64 +
                                 ((((kk << 2) + hi) ^ (row & 7)) << 3));
      }
#pragma unroll
      for (int i = 0; i < 4; ++i)
#pragma unroll
        for (int j = 0; j < 2; ++j)
          acc_s[i][j] = __builtin_amdgcn_mfma_f32_16x16x32_bf16(
              bq[i], bk[j], acc_s[i][j], 0, 0, 0);
    }
    __builtin_amdgcn_s_setprio(0);

#pragma unroll
    for (int i = 0; i < 4; ++i)
#pragma unroll
      for (int rg = 0; rg < 4; ++rg) {
        const unsigned hw = (unsigned)(mw[i][rg] >> (wn * 32));
#pragma unroll
        for (int j = 0; j < 2; ++j)
          if ((hw >> (j * 16 + fr)) & 1)
            racc[i][rg] += __expf(acc_s[i][j][rg] - 1.0f);
      }
  }

  float* dp = denom + ((size_t)(bm >> 2) * Hq + h) * Lseq + q0 + wm * 64;
#pragma unroll
  for (int i = 0; i < 4; ++i)
#pragma unroll
    for (int rg = 0; rg < 4; ++rg) {
      float rs = racc[i][rg];
      rs += __shfl_xor(rs, 1);
      rs += __shfl_xor(rs, 2);
      rs += __shfl_xor(rs, 4);
      rs += __shfl_xor(rs, 8);
      if (fr == 0) atomicAdd(dp + i * 16 + hi * 4 + rg, rs);
    }
}

// =====================================================================
// Pass B: recompute S, normalize with 1/denom, write attn f32 once (NT),
// bounce P through swizzled LDS, fused PV. Fully double-buffered.
// =====================================================================
__global__ __launch_bounds__(256) void fused_attn(
    const bf16* __restrict__ qh, const bf16* __restrict__ qih,
    const bf16* __restrict__ qih_t, const u64* __restrict__ mb,
    const float* __restrict__ denom, float* __restrict__ attn,
    bf16* __restrict__ outh) {
  __shared__ __align__(16) bf16 Qs[128 * 64];
  __shared__ __align__(16) bf16 Ks[2][64 * 64];
  __shared__ __align__(16) bf16 Vs[2][64 * 64];
  __shared__ __align__(16) bf16 Ps[2][128 * 64];

  int z, q0;
  attn_swizzle(blockIdx.x, z, q0);
  const int bm = z >> 4, h = z & 15;

  const int t = threadIdx.x;
  const int lane = t & 63;
  const int wave = t >> 6;
  const int wm = wave & 1, wn = wave >> 1;
  const int fr = lane & 15;
  const int hi = lane >> 4;
  const int sr = t >> 3;
  const int sc = t & 7;

  const bf16* qh_b = qh + ((size_t)bm * Lseq + q0) * Dmod + h * DHq;
  const bf16* qih_b = qih + (size_t)bm * Lseq * Dmod + h * DHq;
  const bf16* vt_b = qih_t + (size_t)z * DHq * Lseq;
  const u64* mrow = mb + (size_t)bm * Lseq * 8;
  float* arow = attn + (size_t)z * Lseq * Lseq;

#pragma unroll
  for (int s = 0; s < 4; ++s) {
    const int r = s * 32 + sr;
    gld_lds16(qh_b + (size_t)r * Dmod + ((sc ^ (r & 7)) << 3),
              Qs + s * 2048 + t * 8);
  }
#pragma unroll
  for (int s = 0; s < 2; ++s) {
    const int r = s * 32 + sr;
    gld_lds16(qih_b + (size_t)r * Dmod + ((sc ^ (r & 7)) << 3),
              Ks[0] + s * 2048 + t * 8);
    gld_lds16(vt_b + (size_t)r * Lseq + ((sc ^ (r & 7)) << 3),
              Vs[0] + s * 2048 + t * 8);
  }

  const float* drow = denom + ((size_t)(bm >> 2) * Hq + h) * Lseq + q0;
  float invd[4][4];
#pragma unroll
  for (int i = 0; i < 4; ++i)
#pragma unroll
    for (int rg = 0; rg < 4; ++rg) {
      const float d = drow[wm * 64 + i * 16 + hi * 4 + rg];
      invd[i][rg] = (d > 0.0f) ? 1.0f / d : 0.0f;
    }

  f32x4 acc_o[4][2] = {};

  for (int kt = 0; kt < 8; ++kt) {
    const int kv0 = kt * 64;
    asm volatile("s_waitcnt vmcnt(0)" ::: "memory");
    __syncthreads();

    if (kt < 7) {
      const int kv1 = kv0 + 64;
#pragma unroll
      for (int s = 0; s < 2; ++s) {
        const int r = s * 32 + sr;
        gld_lds16(qih_b + (size_t)(kv1 + r) * Dmod + ((sc ^ (r & 7)) << 3),
                  Ks[(kt + 1) & 1] + s * 2048 + t * 8);
        gld_lds16(vt_b + (size_t)r * Lseq + kv1 + ((sc ^ (r & 7)) << 3),
                  Vs[(kt + 1) & 1] + s * 2048 + t * 8);
      }
    }

    u64 mw[4][4];
#pragma unroll
    for (int i = 0; i < 4; ++i)
#pragma unroll
      for (int rg = 0; rg < 4; ++rg)
        mw[i][rg] =
            mrow[(size_t)(q0 + wm * 64 + i * 16 + hi * 4 + rg) * 8 + kt];

    const bf16* Kc = Ks[kt & 1];
    f32x4 acc_s[4][2] = {};
    __builtin_amdgcn_s_setprio(1);
#pragma unroll
    for (int kk = 0; kk < 2; ++kk) {
      bf16x8 bq[4], bk[2];
#pragma unroll
      for (int i = 0; i < 4; ++i) {
        const int row = wm * 64 + i * 16 + fr;
        bq[i] = *(const bf16x8*)(Qs + row * 64 +
                                 ((((kk << 2) + hi) ^ (row & 7)) << 3));
      }
#pragma unroll
      for (int j = 0; j < 2; ++j) {
        const int row = wn * 32 + j * 16 + fr;
        bk[j] = *(const bf16x8*)(Kc + row * 64 +
                                 ((((kk << 2) + hi) ^ (row & 7)) << 3));
      }
#pragma unroll
      for (int i = 0; i < 4; ++i)
#pragma unroll
        for (int j = 0; j < 2; ++j)
          acc_s[i][j] = __builtin_amdgcn_mfma_f32_16x16x32_bf16(
              bq[i], bk[j], acc_s[i][j], 0, 0, 0);
    }
    __builtin_amdgcn_s_setprio(0);

    bf16* Pc = Ps[kt & 1];
#pragma unroll
    for (int i = 0; i < 4; ++i)
#pragma unroll
      for (int j = 0; j < 2; ++j)
#pragma unroll
        for (int rg = 0; rg < 4; ++rg) {
          const int ql = wm * 64 + i * 16 + hi * 4 + rg;
          const int cl = wn * 32 + j * 16 + fr;
          const unsigned hw = (unsigned)(mw[i][rg] >> (wn * 32));
          float p = 0.0f;
          if ((hw >> (j * 16 + fr)) & 1)
            p = __expf(acc_s[i][j][rg] - 1.0f) * invd[i][rg];
          __builtin_nontemporal_store(
              p, arow + (size_t)(q0 + ql) * Lseq + kv0 + cl);
          Pc[ql * 64 + (((cl >> 3) ^ (ql & 7)) << 3) + (cl & 7)] = (bf16)p;
        }
    asm volatile("s_waitcnt lgkmcnt(0)" ::: "memory");
    __builtin_amdgcn_s_barrier();

    const bf16* Vc = Vs[kt & 1];
    __builtin_amdgcn_s_setprio(1);
#pragma unroll
    for (int kk = 0; kk < 2; ++kk) {
      bf16x8 ap[4], bv[2];
#pragma unroll
      for (int i = 0; i < 4; ++i) {
        const int row = wm * 64 + i * 16 + fr;
        ap[i] = *(const bf16x8*)(Pc + row * 64 +
                                 ((((kk << 2) + hi) ^ (row & 7)) << 3));
      }
#pragma unroll
      for (int j = 0; j < 2; ++j) {
        const int row = wn * 32 + j * 16 + fr;
        bv[j] = *(const bf16x8*)(Vc + row * 64 +
                                 ((((kk << 2) + hi) ^ (row & 7)) << 3));
      }
#pragma unroll
      for (int i = 0; i < 4; ++i)
#pragma unroll
        for (int j = 0; j < 2; ++j)
          acc_o[i][j] = __builtin_amdgcn_mfma_f32_16x16x32_bf16(
              ap[i], bv[j], acc_o[i][j], 0, 0, 0);
    }
    __builtin_amdgcn_s_setprio(0);
  }

  bf16* Cb = outh + ((size_t)bm * Lseq + q0) * Dmod + h * DHq;
#pragma unroll
  for (int i = 0; i < 4; ++i)
#pragma unroll
    for (int j = 0; j < 2; ++j)
#pragma unroll
      for (int rg = 0; rg < 4; ++rg)
        Cb[(size_t)(wm * 64 + i * 16 + hi * 4 + rg) * Dmod + wn * 32 +
           j * 16 + fr] = (bf16)acc_o[i][j][rg];
}

extern "C" void kernel_launch(void* const* d_in, const int* in_sizes, int n_in,
                              void* d_out, int out_size, void* d_ws,
                              size_t ws_size, hipStream_t stream) {
  const float* q = (const float*)d_in[0];
  // d_in[1] = k, unused by the reference forward
  const float* qi = (const float*)d_in[2];
  const int* mask = (const int*)d_in[3];
  const float* w_qs = (const float*)d_in[4];
  const float* w_qis = (const float*)d_in[5];
  const float* w_fc = (const float*)d_in[6];
  const float* ln_g = (const float*)d_in[7];
  const float* ln_b = (const float*)d_in[8];

  float* out = (float*)d_out;
  const size_t NE = (size_t)Bq * Mq * Lseq * Dmod;  // 8,388,608
  float* attn = out + NE;  // second tuple element (67,108,864 f32)

  // Scratch parked in the attn output region (dead before fused_attn):
  char* attnc = (char*)attn;  // 268 MB available
  bf16* qib = (bf16*)attnc;                       // 16 MB
  bf16* wqs_t = (bf16*)(attnc + (16u << 20));     // 2 MB
  bf16* wqis_t = (bf16*)(attnc + (18u << 20));    // 2 MB

  char* ws = (char*)d_ws;
  const size_t SZ = NE * sizeof(bf16);  // 16 MiB
  bf16* qn = (bf16*)(ws);               // LN out; reused as out_h later
  bf16* qh = (bf16*)(ws + SZ);
  bf16* qih = (bf16*)(ws + 2 * SZ);
  bf16* qih_t = (bf16*)(ws + 3 * SZ);
  bf16* wfc_t = (bf16*)(ws + 4 * SZ);   // must survive to the last GEMM
  float* denom = (float*)(ws + 4 * SZ + (2u << 20));  // [B,H,L] = 128 KB
  u64* mbits = (u64*)(ws + 4 * SZ + (4u << 20));      // [B,M,L,8] = 512 KB
  bf16* outh = qn;                      // qn dead after first projection

  const int ROWS = Bq * Mq * Lseq;  // 8192

  // 1) fused prep: LN + mask bitmask + weight transposes + qi convert
  prep_kernel<<<12032, 256, 0, stream>>>(q, ln_g, ln_b, qn, mask, mbits,
                                         w_qs, wqs_t, w_qis, wqis_t, w_fc,
                                         wfc_t, qi, qib);
  hipMemsetAsync(denom, 0, (size_t)Bq * Hq * Lseq * sizeof(float), stream);

  // 2) both projections (z=0: qh; z=1: qih + fused qih_t transpose)
  gemm_proj<<<dim3(Dmod / 128, ROWS / 128, 2), 256, 0, stream>>>(
      qn, wqs_t, qh, qib, wqis_t, qih, qih_t);

  // 3) Pass A: softmax denominators
  denom_kernel<<<1024, 256, 0, stream>>>(qh, qih, mbits, denom);

  // 4) Pass B: recompute S, normalize, write attn once, fused PV
  fused_attn<<<1024, 256, 0, stream>>>(qh, qih, qih_t, mbits, denom, attn,
                                       outh);

  // 5) out = out_h @ w_fc + q (f32 out, f32 residual)
  gemm_bt_resid<<<dim3(Dmod / 128, ROWS / 128), 256, 0, stream>>>(
      outh, wfc_t, q, out, Dmod, Dmod, Dmod, Dmod);
}